// Round 2
// baseline (1931.940 us; speedup 1.0000x reference)
//
#include <hip/hip_runtime.h>

typedef unsigned short u16;
typedef __attribute__((ext_vector_type(2))) float f32x2;
typedef __attribute__((ext_vector_type(4))) float f32x4;
typedef __attribute__((ext_vector_type(2))) u16 u16x2;
typedef __attribute__((ext_vector_type(4))) u16 u16x4;
typedef __attribute__((ext_vector_type(8))) u16 u16x8;
typedef __attribute__((ext_vector_type(8))) __bf16 bf16x8;

__device__ __forceinline__ float bf2f(u16 u){ unsigned v = ((unsigned)u) << 16; return __builtin_bit_cast(float, v); }
__device__ __forceinline__ u16 f2bf(float f){
  unsigned u = __builtin_bit_cast(unsigned, f);
  u += 0x7fffu + ((u >> 16) & 1u);
  return (u16)(u >> 16);
}
__device__ __forceinline__ f32x4 b4f(u16x4 u){
  f32x4 r; r[0] = bf2f(u[0]); r[1] = bf2f(u[1]); r[2] = bf2f(u[2]); r[3] = bf2f(u[3]); return r;
}
__device__ __forceinline__ void gld16(const void* g, void* l){
  __builtin_amdgcn_global_load_lds((__attribute__((address_space(1))) void*)(void*)g,
                                   (__attribute__((address_space(3))) void*)l, 16, 0, 0);
}
__device__ __forceinline__ float sigmoidf(float x){ return 1.f / (1.f + expf(-x)); }
__device__ __forceinline__ float siluf(float x){ return x / (1.f + expf(-x)); }

// ---------------- cast fp32 -> bf16 (vectorized) ----------------
__global__ __launch_bounds__(256) void k_cast(const float* __restrict__ in, u16* __restrict__ out, int n4){
  int t = blockIdx.x * 256 + threadIdx.x;
  if (t >= n4) return;
  f32x4 v = ((const f32x4*)in)[t];
  u16x4 o;
  o[0] = f2bf(v[0]); o[1] = f2bf(v[1]); o[2] = f2bf(v[2]); o[3] = f2bf(v[3]);
  ((u16x4*)out)[t] = o;
}

// ---------------- transpose + cast: in (K x N) f32 -> out (N x K) bf16 ----------------
// PERM=1: apply qkv/z column permutation (for W_qkvz): n' separates qkv (0..8191) and z (8192..12287)
template<int PERM>
__global__ __launch_bounds__(256) void k_trans(const float* __restrict__ in, u16* __restrict__ out, int K, int N){
  __shared__ float tile[32][33];
  int tx = threadIdx.x, ty = threadIdx.y;
  int n0 = blockIdx.x * 32, k0 = blockIdx.y * 32;
  #pragma unroll
  for (int j = 0; j < 32; j += 8) tile[ty + j][tx] = in[(size_t)(k0 + ty + j) * N + n0 + tx];
  __syncthreads();
  #pragma unroll
  for (int j = 0; j < 32; j += 8){
    int n = n0 + ty + j;
    int np;
    if (PERM){
      int g = n / 768, r = n - g * 768;
      np = (r < 512) ? (g * 512 + r) : (8192 + g * 256 + (r - 512));
    } else np = n;
    out[(size_t)np * K + k0 + tx] = f2bf(tile[tx][ty + j]);
  }
}

// ---------------- bf16 GEMM: A (M x K) rm, Bt (N x K) rm, 128x128 tile, m97 structure ----------------
// MODE 0: f32 out; MODE 2: split bf16 out (cols<8192 -> C (width 8192), else C2 (width 4096))
template<int MODE>
__global__ __launch_bounds__(256) void k_gemm(const u16* __restrict__ A, const u16* __restrict__ Bt,
                                              void* __restrict__ C, void* __restrict__ C2, int N, int K){
  __shared__ u16 As[128 * 32];
  __shared__ u16 Bs[128 * 32];
  const int tid = threadIdx.x;
  const int wave = tid >> 6, lane = tid & 63;
  const int gm = blockIdx.y * 128, gn = blockIdx.x * 128;
  const int c0 = wave * 2, c1 = c0 + 1;
  const int r0 = c0 * 16 + (lane >> 2), r1 = r0 + 16;
  const int kp = (lane & 3) * 8;
  const u16* a0 = A + (size_t)(gm + r0) * K + kp;
  const u16* a1 = A + (size_t)(gm + r1) * K + kp;
  const u16* b0 = Bt + (size_t)(gn + r0) * K + kp;
  const u16* b1 = Bt + (size_t)(gn + r1) * K + kp;
  const int wr = (wave >> 1) * 64, wc = (wave & 1) * 64;
  f32x4 acc[4][4];
  #pragma unroll
  for (int m = 0; m < 4; m++)
    #pragma unroll
    for (int n = 0; n < 4; n++) acc[m][n] = 0.f;
  for (int k0 = 0; k0 < K; k0 += 32){
    __syncthreads();
    gld16(a0 + k0, &As[c0 * 512]);
    gld16(a1 + k0, &As[c1 * 512]);
    gld16(b0 + k0, &Bs[c0 * 512]);
    gld16(b1 + k0, &Bs[c1 * 512]);
    __syncthreads();
    bf16x8 af[4], bfv[4];
    #pragma unroll
    for (int m = 0; m < 4; m++)
      af[m] = __builtin_bit_cast(bf16x8, *(const u16x8*)&As[(wr + m * 16 + (lane & 15)) * 32 + (lane >> 4) * 8]);
    #pragma unroll
    for (int n = 0; n < 4; n++)
      bfv[n] = __builtin_bit_cast(bf16x8, *(const u16x8*)&Bs[(wc + n * 16 + (lane & 15)) * 32 + (lane >> 4) * 8]);
    #pragma unroll
    for (int m = 0; m < 4; m++)
      #pragma unroll
      for (int n = 0; n < 4; n++)
        acc[m][n] = __builtin_amdgcn_mfma_f32_16x16x32_bf16(af[m], bfv[n], acc[m][n], 0, 0, 0);
  }
  #pragma unroll
  for (int m = 0; m < 4; m++){
    int row = gm + wr + m * 16 + (lane >> 4) * 4;
    #pragma unroll
    for (int n = 0; n < 4; n++){
      int col = gn + wc + n * 16 + (lane & 15);
      #pragma unroll
      for (int j = 0; j < 4; j++){
        if (MODE == 0){
          ((float*)C)[(size_t)(row + j) * N + col] = acc[m][n][j];
        } else {
          if (col < 8192) ((u16*)C)[(size_t)(row + j) * 8192 + col]         = f2bf(acc[m][n][j]);
          else            ((u16*)C2)[(size_t)(row + j) * 4096 + col - 8192] = f2bf(acc[m][n][j]);
        }
      }
    }
  }
}

// ---------------- small ba GEMM: hs (4096x2048) f32 @ Wba (2048x64) -> ba (4096x64) ----------------
__global__ __launch_bounds__(256) void k_ba(const float* __restrict__ hs, const float* __restrict__ Wba,
                                            float* __restrict__ ba){
  int wave = threadIdx.x >> 6, lane = threadIdx.x & 63;
  int s0 = (blockIdx.x * 4 + wave) * 4;
  f32x4 acc = 0.f;
  for (int k = 0; k < 2048; k += 4){
    float w0 = Wba[(size_t)(k + 0) * 64 + lane];
    float w1 = Wba[(size_t)(k + 1) * 64 + lane];
    float w2 = Wba[(size_t)(k + 2) * 64 + lane];
    float w3 = Wba[(size_t)(k + 3) * 64 + lane];
    f32x4 h0 = *(const f32x4*)&hs[(size_t)(s0 + 0) * 2048 + k];
    f32x4 h1 = *(const f32x4*)&hs[(size_t)(s0 + 1) * 2048 + k];
    f32x4 h2 = *(const f32x4*)&hs[(size_t)(s0 + 2) * 2048 + k];
    f32x4 h3 = *(const f32x4*)&hs[(size_t)(s0 + 3) * 2048 + k];
    acc[0] += h0[0]*w0 + h0[1]*w1 + h0[2]*w2 + h0[3]*w3;
    acc[1] += h1[0]*w0 + h1[1]*w1 + h1[2]*w2 + h1[3]*w3;
    acc[2] += h2[0]*w0 + h2[1]*w1 + h2[2]*w2 + h2[3]*w3;
    acc[3] += h3[0]*w0 + h3[1]*w1 + h3[2]*w2 + h3[3]*w3;
  }
  #pragma unroll
  for (int r = 0; r < 4; r++) ba[(size_t)(s0 + r) * 64 + lane] = acc[r];
}

// ---------------- causal depthwise conv (K=4) + SiLU over qkvB (4096 x 8192 bf16) ----------------
__global__ __launch_bounds__(256) void k_conv(const u16* __restrict__ qkvB, const float* __restrict__ cw,
                                              float* __restrict__ qc, float* __restrict__ kc, float* __restrict__ vc){
  int idx = blockIdx.x * 256 + threadIdx.x;      // 4096 * 1024
  int c8 = idx & 1023, s = idx >> 10;
  int c = c8 * 8;
  int col; float* outp;
  if (c < 2048)      { int hh = c >> 7, d = c & 127; col = hh * 512 + d;               outp = qc + (size_t)s * 2048 + c; }
  else if (c < 4096) { int cc = c - 2048, hh = cc >> 7, d = cc & 127; col = hh * 512 + 128 + d; outp = kc + (size_t)s * 2048 + cc; }
  else               { int cc = c - 4096, nv = cc >> 7, d = cc & 127;
                       col = (nv >> 1) * 512 + 256 + (nv & 1) * 128 + d;               outp = vc + (size_t)s * 4096 + cc; }
  float w[8][4];
  #pragma unroll
  for (int e = 0; e < 8; e++){
    f32x4 wv = *(const f32x4*)&cw[(size_t)(c + e) * 4];
    #pragma unroll
    for (int j = 0; j < 4; j++) w[e][j] = wv[j];
  }
  float acc[8] = {0.f,0.f,0.f,0.f,0.f,0.f,0.f,0.f};
  #pragma unroll
  for (int j = 0; j < 4; j++){
    int sp = s - 3 + j;
    if (sp < 0) continue;
    u16x8 x = *(const u16x8*)&qkvB[(size_t)sp * 8192 + col];
    #pragma unroll
    for (int e = 0; e < 8; e++) acc[e] += w[e][j] * bf2f(x[e]);
  }
  f32x4 oa, ob;
  #pragma unroll
  for (int e = 0; e < 4; e++) oa[e] = siluf(acc[e]);
  #pragma unroll
  for (int e = 0; e < 4; e++) ob[e] = siluf(acc[e + 4]);
  *(f32x4*)&outp[0] = oa;
  *(f32x4*)&outp[4] = ob;
}

// ---------------- beta / g ----------------
__global__ __launch_bounds__(256) void k_bg(const float* __restrict__ ba, const float* __restrict__ Alog,
                                            const float* __restrict__ dtb, float* __restrict__ betaO,
                                            float* __restrict__ gO){
  int idx = blockIdx.x * 256 + threadIdx.x;   // < 131072
  int s = idx >> 5, nv = idx & 31;
  float b = ba[(size_t)s * 64 + (nv >> 1) * 4 + (nv & 1)];
  float a = ba[(size_t)s * 64 + (nv >> 1) * 4 + 2 + (nv & 1)];
  betaO[idx] = sigmoidf(b);
  float x = a + dtb[nv];
  float sp = (x > 20.f) ? x : log1pf(expf(x));
  gO[idx] = -expf(Alog[nv]) * sp;
}

// ---------------- in-place l2norm of q rows (with dk^-0.5) and k rows ----------------
__global__ __launch_bounds__(256) void k_rownorm(float* __restrict__ qc, float* __restrict__ kc){
  int wave = threadIdx.x >> 6, lane = threadIdx.x & 63;
  int row = blockIdx.x * 4 + wave;  // 0..131071 ; first 65536 = q rows
  float* p = (row < 65536) ? (qc + (size_t)row * 128) : (kc + (size_t)(row - 65536) * 128);
  float sc = (row < 65536) ? 0.08838834764831845f : 1.f;
  f32x2 v = ((const f32x2*)p)[lane];
  float ss = v[0] * v[0] + v[1] * v[1];
  #pragma unroll
  for (int off = 32; off; off >>= 1) ss += __shfl_xor(ss, off);
  float inv = rsqrtf(ss + 1e-6f) * sc;
  v[0] *= inv; v[1] *= inv;
  ((f32x2*)p)[lane] = v;
}

// ---------------- per-(head,chunk) precompute: gcum, attn_local, v_c, k_cumdecay ----------------
__global__ __launch_bounds__(256) void k_pre(const float* __restrict__ qc, const float* __restrict__ kc,
    const float* __restrict__ vc, const float* __restrict__ betaB, const float* __restrict__ gB,
    float* __restrict__ gcum, u16* __restrict__ attnO, u16* __restrict__ vcrO, u16* __restrict__ kcdO){
  __shared__ float sK[64 * 132];
  __shared__ float sM[64 * 68];
  __shared__ float sX[64 * 264];   // sQ aliases first 64*132 floats (disjoint lifetime)
  __shared__ float sG[64];
  __shared__ float sBeta[64];
  float* sQ = sX;
  const int tid = threadIdx.x;
  const int nv = blockIdx.x & 31, chunk = blockIdx.x >> 5;
  const int h = nv >> 1, s0 = chunk * 64;
  if (tid < 64){
    float g = gB[(size_t)(s0 + tid) * 32 + nv];
    #pragma unroll
    for (int off = 1; off < 64; off <<= 1){ float nb = __shfl_up(g, off); if (tid >= off) g += nb; }
    sG[tid] = g;
    gcum[(size_t)(s0 + tid) * 32 + nv] = g;
  } else if (tid < 128){
    sBeta[tid - 64] = betaB[(size_t)(s0 + tid - 64) * 32 + nv];
  }
  for (int t = tid; t < 2048; t += 256){
    int i = t >> 5, d = (t & 31) * 4;
    *(f32x4*)&sK[i * 132 + d] = *(const f32x4*)&kc[(size_t)(s0 + i) * 2048 + h * 128 + d];
    *(f32x4*)&sQ[i * 132 + d] = *(const f32x4*)&qc[(size_t)(s0 + i) * 2048 + h * 128 + d];
  }
  __syncthreads();
  // fused M (k_beta . k) and attn (q . k), 64x64x128
  const int jb = tid & 15, ib = tid >> 4;
  float mA[4][4] = {}, aA[4][4] = {};
  for (int k = 0; k < 128; k += 4){
    f32x4 kA[4], qA[4], kB[4];
    #pragma unroll
    for (int r = 0; r < 4; r++){
      kA[r] = *(const f32x4*)&sK[(ib * 4 + r) * 132 + k];
      qA[r] = *(const f32x4*)&sQ[(ib * 4 + r) * 132 + k];
      kB[r] = *(const f32x4*)&sK[(jb * 4 + r) * 132 + k];
    }
    #pragma unroll
    for (int r = 0; r < 4; r++)
      #pragma unroll
      for (int c2 = 0; c2 < 4; c2++)
        #pragma unroll
        for (int kk = 0; kk < 4; kk++){
          mA[r][c2] += kA[r][kk] * kB[c2][kk];
          aA[r][c2] += qA[r][kk] * kB[c2][kk];
        }
  }
  #pragma unroll
  for (int r = 0; r < 4; r++){
    int i = ib * 4 + r;
    float gi = sG[i], bi = sBeta[i];
    f32x4 mrow;
    u16x4 arow;
    #pragma unroll
    for (int c2 = 0; c2 < 4; c2++){
      int j = jb * 4 + c2;
      float dec = expf(gi - sG[j]);
      mrow[c2] = (i > j)  ? mA[r][c2] * bi * dec : 0.f;
      arow[c2] = f2bf((i >= j) ? aA[r][c2] * dec : 0.f);
    }
    *(f32x4*)&sM[i * 68 + jb * 4] = mrow;
    *(u16x4*)&attnO[(((size_t)nv * 64 + chunk) * 64 + i) * 64 + jb * 4] = arow;
  }
  __syncthreads();
  // X = [ v*beta | k*beta*exp(g) ]  (64 x 256), overwrites sQ region
  for (int t = tid; t < 2048; t += 256){
    int i = t >> 5, d = (t & 31) * 4;
    float bi = sBeta[i];
    f32x4 v = *(const f32x4*)&vc[(size_t)(s0 + i) * 4096 + nv * 128 + d];
    v *= bi;
    *(f32x4*)&sX[i * 264 + d] = v;
    f32x4 kb = *(const f32x4*)&sK[i * 132 + d];
    kb *= bi * expf(sG[i]);
    *(f32x4*)&sX[i * 264 + 128 + d] = kb;
  }
  __syncthreads();
  // forward substitution (I+M) x = rhs; each thread owns one of 256 columns in registers
  float x[64];
  #pragma unroll
  for (int i = 0; i < 64; i++) x[i] = sX[i * 264 + tid];
  #pragma unroll
  for (int i = 1; i < 64; i++){
    #pragma unroll
    for (int j = 0; j < i; j++) x[i] -= sM[i * 68 + j] * x[j];
  }
  u16* outp = (tid < 128) ? (vcrO + ((size_t)nv * 4096 + s0) * 128 + tid)
                          : (kcdO + ((size_t)nv * 4096 + s0) * 128 + (tid - 128));
  #pragma unroll
  for (int i = 0; i < 64; i++) outp[(size_t)i * 128] = f2bf(x[i]);
}

// ---------------- sequential inter-chunk scan; block = (head nv, 16-col state slice) ----------------
__global__ __launch_bounds__(256) void k_scan(const float* __restrict__ qc, const float* __restrict__ kc,
    const u16* __restrict__ vcr, const u16* __restrict__ kcd, const u16* __restrict__ attnB,
    const float* __restrict__ gcum, float* __restrict__ core){
  __shared__ float sS[128 * 16];
  __shared__ float sKCD[64 * 132];
  __shared__ float sQ[64 * 132];
  __shared__ float sK[64 * 132];
  __shared__ float sA[64 * 68];
  __shared__ float sV[64 * 16];
  __shared__ float sEg[64];
  __shared__ float sEd[64];
  const int tid = threadIdx.x;
  const int nv = blockIdx.x & 31, vg = blockIdx.x >> 5;
  const int h = nv >> 1, v0 = vg * 16;
  for (int t = tid; t < 2048; t += 256) sS[t] = 0.f;
  const int i2 = tid >> 2, c4 = (tid & 3) * 4;
  const int k5 = tid >> 1, c8 = (tid & 1) * 8;
  for (int chunk = 0; chunk < 64; ++chunk){
    const int s0 = chunk * 64;
    __syncthreads();
    if (tid < 64){
      float gv = gcum[(size_t)(s0 + tid) * 32 + nv];
      float gl = gcum[(size_t)(s0 + 63) * 32 + nv];
      sEg[tid] = expf(gv);
      sEd[tid] = expf(gl - gv);
    }
    for (int t = tid; t < 2048; t += 256){
      int i = t >> 5, d = (t & 31) * 4;
      *(f32x4*)&sKCD[i * 132 + d] = b4f(*(const u16x4*)&kcd[((size_t)nv * 4096 + s0 + i) * 128 + d]);
      *(f32x4*)&sK[i * 132 + d]   = *(const f32x4*)&kc[(size_t)(s0 + i) * 2048 + h * 128 + d];
    }
    for (int t = tid; t < 1024; t += 256){
      int i = t >> 4, j4 = (t & 15) * 4;
      *(f32x4*)&sA[i * 68 + j4] = b4f(*(const u16x4*)&attnB[(((size_t)nv * 64 + chunk) * 64 + i) * 64 + j4]);
    }
    { int i = tid >> 2, d = (tid & 3) * 4;
      *(f32x4*)&sV[i * 16 + d] = b4f(*(const u16x4*)&vcr[((size_t)nv * 4096 + s0 + i) * 128 + v0 + d]); }
    __syncthreads();
    for (int t = tid; t < 2048; t += 256){
      int i = t >> 5, d = (t & 31) * 4;
      f32x4 qv = *(const f32x4*)&qc[(size_t)(s0 + i) * 2048 + h * 128 + d];
      qv *= sEg[i];
      *(f32x4*)&sQ[i * 132 + d] = qv;
    }
    __syncthreads();
    // v_prime = kcd @ S ; attn_inter = (q e^g) @ S
    f32x4 vp = 0.f, ai = 0.f;
    for (int k = 0; k < 128; k += 4){
      f32x4 kc4 = *(const f32x4*)&sKCD[i2 * 132 + k];
      f32x4 q4  = *(const f32x4*)&sQ[i2 * 132 + k];
      #pragma unroll
      for (int kk = 0; kk < 4; kk++){
        f32x4 srow = *(const f32x4*)&sS[(k + kk) * 16 + c4];
        vp += kc4[kk] * srow;
        ai += q4[kk] * srow;
      }
    }
    f32x4 vn = *(const f32x4*)&sV[i2 * 16 + c4] - vp;
    *(f32x4*)&sV[i2 * 16 + c4] = vn;
    __syncthreads();
    // out = attn_inter + attn_local @ v_new
    f32x4 o = ai;
    for (int j = 0; j < 64; j += 4){
      f32x4 a4 = *(const f32x4*)&sA[i2 * 68 + j];
      #pragma unroll
      for (int jj = 0; jj < 4; jj++){
        f32x4 vrow = *(const f32x4*)&sV[(j + jj) * 16 + c4];
        o += a4[jj] * vrow;
      }
    }
    *(f32x4*)&core[((size_t)(s0 + i2) * 32 + nv) * 128 + v0 + c4] = o;
    // S = S*exp(g_last) + (k*exp(g_last-g))^T @ v_new
    f32x4 dla = 0.f, dlb = 0.f;
    for (int i = 0; i < 64; i++){
      float kv = sK[i * 132 + k5] * sEd[i];
      f32x4 va = *(const f32x4*)&sV[i * 16 + c8];
      f32x4 vb = *(const f32x4*)&sV[i * 16 + c8 + 4];
      dla += kv * va;
      dlb += kv * vb;
    }
    float eL = sEg[63];
    f32x4 sa = *(const f32x4*)&sS[k5 * 16 + c8];
    f32x4 sb = *(const f32x4*)&sS[k5 * 16 + c8 + 4];
    *(f32x4*)&sS[k5 * 16 + c8]     = sa * eL + dla;
    *(f32x4*)&sS[k5 * 16 + c8 + 4] = sb * eL + dlb;
  }
}

// ---------------- RMSNorm * norm_weight * silu(z) -> bf16 ----------------
__global__ __launch_bounds__(256) void k_gate(const float* __restrict__ core, const u16* __restrict__ zB,
                                              const float* __restrict__ nw, u16* __restrict__ hb){
  int wave = threadIdx.x >> 6, lane = threadIdx.x & 63;
  int row = blockIdx.x * 4 + wave;    // s*32 + nv
  int s = row >> 5, nv = row & 31;
  const float* cp = core + (size_t)row * 128;
  f32x2 c = ((const f32x2*)cp)[lane];
  float ss = c[0] * c[0] + c[1] * c[1];
  #pragma unroll
  for (int off = 32; off; off >>= 1) ss += __shfl_xor(ss, off);
  float rms = rsqrtf(ss * (1.f / 128.f) + 1e-6f);
  int zcol = (nv >> 1) * 256 + (nv & 1) * 128 + lane * 2;
  u16x2 zu = *(const u16x2*)&zB[(size_t)s * 4096 + zcol];
  float z0 = siluf(bf2f(zu[0])), z1 = siluf(bf2f(zu[1]));
  u16x2 ho;
  ho[0] = f2bf(c[0] * rms * nw[lane * 2]     * z0);
  ho[1] = f2bf(c[1] * rms * nw[lane * 2 + 1] * z1);
  *(u16x2*)&hb[(size_t)row * 128 + lane * 2] = ho;
}

extern "C" void kernel_launch(void* const* d_in, const int* in_sizes, int n_in,
                              void* d_out, int out_size, void* d_ws, size_t ws_size,
                              hipStream_t stream){
  (void)in_sizes; (void)n_in; (void)out_size; (void)ws_size;
  const float* hs    = (const float*)d_in[0];
  const float* Wqkvz = (const float*)d_in[1];
  const float* Wba   = (const float*)d_in[2];
  const float* cw    = (const float*)d_in[3];
  const float* dtb   = (const float*)d_in[4];
  const float* Alog  = (const float*)d_in[5];
  const float* nw    = (const float*)d_in[6];
  const float* Wout  = (const float*)d_in[7];
  char* ws = (char*)d_ws;
  const size_t MB = 1ull << 20;
  // Region R1 (64MB): [hsb 16 | wqT 48] -> vc f32 -> coreB f32
  u16*   hsb   = (u16*)  (ws + 0);
  u16*   wqT   = (u16*)  (ws + 16 * MB);
  float* vc    = (float*)(ws + 0);
  float* coreB = (float*)(ws + 0);
  // Region R2 (64MB): qkvB bf16 -> [vcrB bf16 32 | kcdB bf16 32]
  u16*   qkvB  = (u16*)  (ws + 64 * MB);
  u16*   vcrB  = (u16*)  (ws + 64 * MB);
  u16*   kcdB  = (u16*)  (ws + 96 * MB);
  // Region R3 (32MB): zB bf16
  u16*   zB    = (u16*)  (ws + 128 * MB);
  // Region R4 (32MB): qc f32 -> hb bf16
  float* qc    = (float*)(ws + 160 * MB);
  u16*   hb    = (u16*)  (ws + 160 * MB);
  // Region R5 (32MB): kc f32 -> woT bf16
  float* kc    = (float*)(ws + 192 * MB);
  u16*   woT   = (u16*)  (ws + 192 * MB);
  // Region R6 (16MB): attnB bf16
  u16*   attnB = (u16*)  (ws + 224 * MB);
  // Region R7 (~2.5MB): small
  float* ba    = (float*)(ws + 240 * MB);
  float* betaB = (float*)(ws + 241 * MB);
  float* gB    = (float*)(ws + 241 * MB + 512 * 1024);
  float* gcum  = (float*)(ws + 242 * MB);
  float* out   = (float*)d_out;

  k_cast<<<8192, 256, 0, stream>>>(hs, hsb, 2097152);
  k_trans<1><<<dim3(384, 64), dim3(32, 8), 0, stream>>>(Wqkvz, wqT, 2048, 12288);
  k_gemm<2><<<dim3(96, 32), 256, 0, stream>>>(hsb, wqT, qkvB, zB, 12288, 2048);
  k_ba<<<256, 256, 0, stream>>>(hs, Wba, ba);
  k_bg<<<512, 256, 0, stream>>>(ba, Alog, dtb, betaB, gB);
  k_conv<<<16384, 256, 0, stream>>>(qkvB, cw, qc, kc, vc);
  k_rownorm<<<32768, 256, 0, stream>>>(qc, kc);
  k_pre<<<2048, 256, 0, stream>>>(qc, kc, vc, betaB, gB, gcum, attnB, vcrB, kcdB);
  k_scan<<<256, 256, 0, stream>>>(qc, kc, vcrB, kcdB, attnB, gcum, coreB);
  k_gate<<<32768, 256, 0, stream>>>(coreB, zB, nw, hb);
  k_trans<0><<<dim3(64, 128), dim3(32, 8), 0, stream>>>(Wout, woT, 4096, 2048);
  k_gemm<0><<<dim3(16, 32), 256, 0, stream>>>(hb, woT, out, nullptr, 2048, 4096);
}

// Round 3
// 1640.172 us; speedup vs baseline: 1.1779x; 1.1779x over previous
//
#include <hip/hip_runtime.h>

typedef unsigned short u16;
typedef __attribute__((ext_vector_type(2))) float f32x2;
typedef __attribute__((ext_vector_type(4))) float f32x4;
typedef __attribute__((ext_vector_type(2))) u16 u16x2;
typedef __attribute__((ext_vector_type(4))) u16 u16x4;
typedef __attribute__((ext_vector_type(8))) u16 u16x8;
typedef __attribute__((ext_vector_type(8))) __bf16 bf16x8;

__device__ __forceinline__ float bf2f(u16 u){ unsigned v = ((unsigned)u) << 16; return __builtin_bit_cast(float, v); }
__device__ __forceinline__ u16 f2bf(float f){
  unsigned u = __builtin_bit_cast(unsigned, f);
  u += 0x7fffu + ((u >> 16) & 1u);
  return (u16)(u >> 16);
}
__device__ __forceinline__ f32x4 b4f(u16x4 u){
  f32x4 r; r[0] = bf2f(u[0]); r[1] = bf2f(u[1]); r[2] = bf2f(u[2]); r[3] = bf2f(u[3]); return r;
}
__device__ __forceinline__ void gld16(const void* g, const void* l){
  __builtin_amdgcn_global_load_lds((__attribute__((address_space(1))) void*)(void*)g,
                                   (__attribute__((address_space(3))) void*)(void*)l, 16, 0, 0);
}
__device__ __forceinline__ float sigmoidf(float x){ return 1.f / (1.f + expf(-x)); }
__device__ __forceinline__ float siluf(float x){ return x / (1.f + expf(-x)); }

// ---------------- cast fp32 -> bf16 ----------------
__global__ __launch_bounds__(256) void k_cast(const float* __restrict__ in, u16* __restrict__ out, int n4){
  int t = blockIdx.x * 256 + threadIdx.x;
  if (t >= n4) return;
  f32x4 v = ((const f32x4*)in)[t];
  u16x4 o;
  o[0] = f2bf(v[0]); o[1] = f2bf(v[1]); o[2] = f2bf(v[2]); o[3] = f2bf(v[3]);
  ((u16x4*)out)[t] = o;
}

// ---------------- transpose + cast: in (K x N) f32 -> out (N x K) bf16 ----------------
template<int PERM>
__global__ __launch_bounds__(256) void k_trans(const float* __restrict__ in, u16* __restrict__ out, int K, int N){
  __shared__ float tile[32][33];
  int tx = threadIdx.x, ty = threadIdx.y;
  int n0 = blockIdx.x * 32, k0 = blockIdx.y * 32;
  #pragma unroll
  for (int j = 0; j < 32; j += 8) tile[ty + j][tx] = in[(size_t)(k0 + ty + j) * N + n0 + tx];
  __syncthreads();
  #pragma unroll
  for (int j = 0; j < 32; j += 8){
    int n = n0 + ty + j;
    int np;
    if (PERM){
      int g = n / 768, r = n - g * 768;
      np = (r < 512) ? (g * 512 + r) : (8192 + g * 256 + (r - 512));
    } else np = n;
    out[(size_t)np * K + k0 + tx] = f2bf(tile[tx][ty + j]);
  }
}

// ---------------- bf16 GEMM (m97 structure) ----------------
template<int MODE>
__global__ __launch_bounds__(256) void k_gemm(const u16* __restrict__ A, const u16* __restrict__ Bt,
                                              void* __restrict__ C, void* __restrict__ C2, int N, int K){
  __shared__ u16 As[128 * 32];
  __shared__ u16 Bs[128 * 32];
  const int tid = threadIdx.x;
  const int wave = tid >> 6, lane = tid & 63;
  const int gm = blockIdx.y * 128, gn = blockIdx.x * 128;
  const int c0 = wave * 2, c1 = c0 + 1;
  const int r0 = c0 * 16 + (lane >> 2), r1 = r0 + 16;
  const int kp = (lane & 3) * 8;
  const u16* a0 = A + (size_t)(gm + r0) * K + kp;
  const u16* a1 = A + (size_t)(gm + r1) * K + kp;
  const u16* b0 = Bt + (size_t)(gn + r0) * K + kp;
  const u16* b1 = Bt + (size_t)(gn + r1) * K + kp;
  const int wr = (wave >> 1) * 64, wc = (wave & 1) * 64;
  f32x4 acc[4][4];
  #pragma unroll
  for (int m = 0; m < 4; m++)
    #pragma unroll
    for (int n = 0; n < 4; n++) acc[m][n] = 0.f;
  for (int k0 = 0; k0 < K; k0 += 32){
    __syncthreads();
    gld16(a0 + k0, &As[c0 * 512]);
    gld16(a1 + k0, &As[c1 * 512]);
    gld16(b0 + k0, &Bs[c0 * 512]);
    gld16(b1 + k0, &Bs[c1 * 512]);
    __syncthreads();
    bf16x8 af[4], bfv[4];
    #pragma unroll
    for (int m = 0; m < 4; m++)
      af[m] = __builtin_bit_cast(bf16x8, *(const u16x8*)&As[(wr + m * 16 + (lane & 15)) * 32 + (lane >> 4) * 8]);
    #pragma unroll
    for (int n = 0; n < 4; n++)
      bfv[n] = __builtin_bit_cast(bf16x8, *(const u16x8*)&Bs[(wc + n * 16 + (lane & 15)) * 32 + (lane >> 4) * 8]);
    #pragma unroll
    for (int m = 0; m < 4; m++)
      #pragma unroll
      for (int n = 0; n < 4; n++)
        acc[m][n] = __builtin_amdgcn_mfma_f32_16x16x32_bf16(af[m], bfv[n], acc[m][n], 0, 0, 0);
  }
  #pragma unroll
  for (int m = 0; m < 4; m++){
    int row = gm + wr + m * 16 + (lane >> 4) * 4;
    #pragma unroll
    for (int n = 0; n < 4; n++){
      int col = gn + wc + n * 16 + (lane & 15);
      #pragma unroll
      for (int j = 0; j < 4; j++){
        if (MODE == 0){
          ((float*)C)[(size_t)(row + j) * N + col] = acc[m][n][j];
        } else {
          if (col < 8192) ((u16*)C)[(size_t)(row + j) * 8192 + col]         = f2bf(acc[m][n][j]);
          else            ((u16*)C2)[(size_t)(row + j) * 4096 + col - 8192] = f2bf(acc[m][n][j]);
        }
      }
    }
  }
}

// ---------------- small ba GEMM ----------------
__global__ __launch_bounds__(256) void k_ba(const float* __restrict__ hs, const float* __restrict__ Wba,
                                            float* __restrict__ ba){
  int wave = threadIdx.x >> 6, lane = threadIdx.x & 63;
  int s0 = (blockIdx.x * 4 + wave) * 4;
  f32x4 acc = 0.f;
  for (int k = 0; k < 2048; k += 4){
    float w0 = Wba[(size_t)(k + 0) * 64 + lane];
    float w1 = Wba[(size_t)(k + 1) * 64 + lane];
    float w2 = Wba[(size_t)(k + 2) * 64 + lane];
    float w3 = Wba[(size_t)(k + 3) * 64 + lane];
    f32x4 h0 = *(const f32x4*)&hs[(size_t)(s0 + 0) * 2048 + k];
    f32x4 h1 = *(const f32x4*)&hs[(size_t)(s0 + 1) * 2048 + k];
    f32x4 h2 = *(const f32x4*)&hs[(size_t)(s0 + 2) * 2048 + k];
    f32x4 h3 = *(const f32x4*)&hs[(size_t)(s0 + 3) * 2048 + k];
    acc[0] += h0[0]*w0 + h0[1]*w1 + h0[2]*w2 + h0[3]*w3;
    acc[1] += h1[0]*w0 + h1[1]*w1 + h1[2]*w2 + h1[3]*w3;
    acc[2] += h2[0]*w0 + h2[1]*w1 + h2[2]*w2 + h2[3]*w3;
    acc[3] += h3[0]*w0 + h3[1]*w1 + h3[2]*w2 + h3[3]*w3;
  }
  #pragma unroll
  for (int r = 0; r < 4; r++) ba[(size_t)(s0 + r) * 64 + lane] = acc[r];
}

// ---------------- causal dwconv(K=4)+SiLU; q/k -> f32, v -> bf16 ----------------
__global__ __launch_bounds__(256) void k_conv(const u16* __restrict__ qkvB, const float* __restrict__ cw,
                                              float* __restrict__ qcF, float* __restrict__ kcF, u16* __restrict__ vcB){
  int idx = blockIdx.x * 256 + threadIdx.x;      // 4096 * 1024
  int c8 = idx & 1023, s = idx >> 10;
  int c = c8 * 8;
  int col;
  if (c < 2048)      { int hh = c >> 7, d = c & 127; col = hh * 512 + d; }
  else if (c < 4096) { int cc = c - 2048, hh = cc >> 7, d = cc & 127; col = hh * 512 + 128 + d; }
  else               { int cc = c - 4096, nv = cc >> 7, d = cc & 127; col = (nv >> 1) * 512 + 256 + (nv & 1) * 128 + d; }
  float w[8][4];
  #pragma unroll
  for (int e = 0; e < 8; e++){
    f32x4 wv = *(const f32x4*)&cw[(size_t)(c + e) * 4];
    #pragma unroll
    for (int j = 0; j < 4; j++) w[e][j] = wv[j];
  }
  float acc[8] = {0.f,0.f,0.f,0.f,0.f,0.f,0.f,0.f};
  #pragma unroll
  for (int j = 0; j < 4; j++){
    int sp = s - 3 + j;
    if (sp < 0) continue;
    u16x8 x = *(const u16x8*)&qkvB[(size_t)sp * 8192 + col];
    #pragma unroll
    for (int e = 0; e < 8; e++) acc[e] += w[e][j] * bf2f(x[e]);
  }
  if (c < 4096){
    float* outp = (c < 2048) ? qcF + (size_t)s * 2048 + c : kcF + (size_t)s * 2048 + (c - 2048);
    f32x4 oa, ob;
    #pragma unroll
    for (int e = 0; e < 4; e++) oa[e] = siluf(acc[e]);
    #pragma unroll
    for (int e = 0; e < 4; e++) ob[e] = siluf(acc[e + 4]);
    *(f32x4*)&outp[0] = oa;
    *(f32x4*)&outp[4] = ob;
  } else {
    u16x8 ov;
    #pragma unroll
    for (int e = 0; e < 8; e++) ov[e] = f2bf(siluf(acc[e]));
    *(u16x8*)&vcB[(size_t)s * 4096 + (c - 4096)] = ov;
  }
}

// ---------------- beta / g ----------------
__global__ __launch_bounds__(256) void k_bg(const float* __restrict__ ba, const float* __restrict__ Alog,
                                            const float* __restrict__ dtb, float* __restrict__ betaO,
                                            float* __restrict__ gO){
  int idx = blockIdx.x * 256 + threadIdx.x;   // < 131072
  int s = idx >> 5, nv = idx & 31;
  float b = ba[(size_t)s * 64 + (nv >> 1) * 4 + (nv & 1)];
  float a = ba[(size_t)s * 64 + (nv >> 1) * 4 + 2 + (nv & 1)];
  betaO[idx] = sigmoidf(b);
  float x = a + dtb[nv];
  float sp = (x > 20.f) ? x : log1pf(expf(x));
  gO[idx] = -expf(Alog[nv]) * sp;
}

// ---------------- l2norm rows: f32 in -> bf16 out ----------------
__global__ __launch_bounds__(256) void k_rownorm(const float* __restrict__ qcF, const float* __restrict__ kcF,
                                                 u16* __restrict__ qcB, u16* __restrict__ kcB){
  int wave = threadIdx.x >> 6, lane = threadIdx.x & 63;
  int row = blockIdx.x * 4 + wave;  // first 65536 = q rows
  const float* src = (row < 65536) ? qcF + (size_t)row * 128 : kcF + (size_t)(row - 65536) * 128;
  u16* dst = (row < 65536) ? qcB + (size_t)row * 128 : kcB + (size_t)(row - 65536) * 128;
  float sc = (row < 65536) ? 0.08838834764831845f : 1.f;
  f32x2 v = ((const f32x2*)src)[lane];
  float ss = v[0] * v[0] + v[1] * v[1];
  #pragma unroll
  for (int off = 32; off; off >>= 1) ss += __shfl_xor(ss, off);
  float inv = rsqrtf(ss + 1e-6f) * sc;
  u16x2 o; o[0] = f2bf(v[0] * inv); o[1] = f2bf(v[1] * inv);
  ((u16x2*)dst)[lane] = o;
}

// ---------------- per-(nv,chunk) precompute; emits packed swizzled scan blocks ----------------
// scanA block (stride 25600B): [kcd 16KB swz | attn 8KB swz | eg 256B | ed 256B | pad 512B]
// scanB block (stride 32768B, per (h,chunk), written by even nv): [q 16KB swz | kT 16KB swz]
__global__ __launch_bounds__(256) void k_pre(const u16* __restrict__ qcB, const u16* __restrict__ kcB,
    const u16* __restrict__ vcB, const float* __restrict__ betaB, const float* __restrict__ gB,
    char* __restrict__ scanA, char* __restrict__ scanBg, u16* __restrict__ vcrG){
  __shared__ float sK[64 * 132];
  __shared__ float sX[64 * 264];   // sQ aliases first part (disjoint lifetime)
  __shared__ float sM[64 * 68];
  __shared__ float sG[64];
  __shared__ float sEg[64];
  __shared__ float sBeta[64];
  float* sQ = sX;
  const int tid = threadIdx.x;
  const int nv = blockIdx.x & 31, chunk = blockIdx.x >> 5;
  const int h = nv >> 1, s0 = chunk * 64;
  char* gA = scanA + ((size_t)nv * 64 + chunk) * 25600;
  u16* kcdG = (u16*)gA;
  u16* attnG = (u16*)(gA + 16384);
  float* egG = (float*)(gA + 24576);
  char* gB2 = scanBg + ((size_t)h * 64 + chunk) * 32768;
  u16* qG  = (u16*)gB2;
  u16* ktG = (u16*)(gB2 + 16384);
  if (tid < 64){
    float g = gB[(size_t)(s0 + tid) * 32 + nv];
    #pragma unroll
    for (int off = 1; off < 64; off <<= 1){ float nb = __shfl_up(g, off); if (tid >= off) g += nb; }
    sG[tid] = g;
    float g63 = __shfl(g, 63);
    float eg = expf(g);
    sEg[tid] = eg;
    egG[tid] = eg;
    egG[64 + tid] = expf(g63 - g);
  } else if (tid < 128){
    sBeta[tid - 64] = betaB[(size_t)(s0 + tid - 64) * 32 + nv];
  }
  for (int t = tid; t < 2048; t += 256){
    int i = t >> 5, d = (t & 31) * 4;
    *(f32x4*)&sK[i * 132 + d] = b4f(*(const u16x4*)&kcB[(size_t)(s0 + i) * 2048 + h * 128 + d]);
    *(f32x4*)&sQ[i * 132 + d] = b4f(*(const u16x4*)&qcB[(size_t)(s0 + i) * 2048 + h * 128 + d]);
  }
  __syncthreads();
  // fused M (k_beta.k) and attn (q.k), 64x64x128
  const int jb = tid & 15, ib = tid >> 4;
  float mA[4][4] = {}, aA[4][4] = {};
  for (int k = 0; k < 128; k += 4){
    f32x4 kA[4], qA[4], kB[4];
    #pragma unroll
    for (int r = 0; r < 4; r++){
      kA[r] = *(const f32x4*)&sK[(ib * 4 + r) * 132 + k];
      qA[r] = *(const f32x4*)&sQ[(ib * 4 + r) * 132 + k];
      kB[r] = *(const f32x4*)&sK[(jb * 4 + r) * 132 + k];
    }
    #pragma unroll
    for (int r = 0; r < 4; r++)
      #pragma unroll
      for (int c2 = 0; c2 < 4; c2++)
        #pragma unroll
        for (int kk = 0; kk < 4; kk++){
          mA[r][c2] += kA[r][kk] * kB[c2][kk];
          aA[r][c2] += qA[r][kk] * kB[c2][kk];
        }
  }
  #pragma unroll
  for (int r = 0; r < 4; r++){
    int i = ib * 4 + r;
    float gi = sG[i], bi = sBeta[i];
    f32x4 mrow;
    u16x4 arow;
    #pragma unroll
    for (int c2 = 0; c2 < 4; c2++){
      int j = jb * 4 + c2;
      float dec = expf(gi - sG[j]);
      mrow[c2] = (i > j)  ? mA[r][c2] * bi * dec : 0.f;
      arow[c2] = f2bf((i >= j) ? aA[r][c2] * dec : 0.f);
    }
    *(f32x4*)&sM[i * 68 + jb * 4] = mrow;
    *(u16x4*)&attnG[i * 64 + ((jb * 4) ^ ((i & 7) << 3))] = arow;
  }
  // scanB outputs (one writer per h): raw q [i][k] swz, kT [k][i] swz
  if (!(nv & 1)){
    for (int t = tid; t < 2048; t += 256){
      int i = t >> 5, d = (t & 31) * 4;
      f32x4 qv = *(const f32x4*)&sQ[i * 132 + d];
      u16x4 o; o[0]=f2bf(qv[0]); o[1]=f2bf(qv[1]); o[2]=f2bf(qv[2]); o[3]=f2bf(qv[3]);
      *(u16x4*)&qG[i * 128 + (d ^ ((i & 7) << 3))] = o;
    }
    for (int t = tid; t < 2048; t += 256){
      int k = t & 127, i0 = (t >> 7) * 4;
      u16x4 o;
      #pragma unroll
      for (int r = 0; r < 4; r++) o[r] = f2bf(sK[(i0 + r) * 132 + k]);
      *(u16x4*)&ktG[k * 64 + (i0 ^ ((k & 7) << 3))] = o;
    }
  }
  __syncthreads();
  // X = [ v*beta | k*beta*exp(g) ]  (64 x 256), overwrites sQ region
  for (int t = tid; t < 2048; t += 256){
    int i = t >> 5, d = (t & 31) * 4;
    float bi = sBeta[i];
    f32x4 v = b4f(*(const u16x4*)&vcB[(size_t)(s0 + i) * 4096 + nv * 128 + d]);
    v *= bi;
    *(f32x4*)&sX[i * 264 + d] = v;
    f32x4 kb = *(const f32x4*)&sK[i * 132 + d];
    kb *= bi * sEg[i];
    *(f32x4*)&sX[i * 264 + 128 + d] = kb;
  }
  __syncthreads();
  // forward substitution; each thread owns one of 256 columns
  float x[64];
  #pragma unroll
  for (int i = 0; i < 64; i++) x[i] = sX[i * 264 + tid];
  #pragma unroll
  for (int i = 1; i < 64; i++){
    #pragma unroll
    for (int j = 0; j < i; j++) x[i] -= sM[i * 68 + j] * x[j];
  }
  #pragma unroll
  for (int i = 0; i < 64; i++) sX[i * 264 + tid] = x[i];
  __syncthreads();
  // cooperative packed outputs: vcr plain, kcd swizzled
  for (int t = tid; t < 2048; t += 256){
    int i = t >> 5, d = (t & 31) * 4;
    u16x4 a; a[0]=f2bf(sX[i*264+d]); a[1]=f2bf(sX[i*264+d+1]); a[2]=f2bf(sX[i*264+d+2]); a[3]=f2bf(sX[i*264+d+3]);
    *(u16x4*)&vcrG[((size_t)nv * 4096 + s0 + i) * 128 + d] = a;
    u16x4 b; b[0]=f2bf(sX[i*264+128+d]); b[1]=f2bf(sX[i*264+128+d+1]); b[2]=f2bf(sX[i*264+128+d+2]); b[3]=f2bf(sX[i*264+128+d+3]);
    *(u16x4*)&kcdG[i * 128 + (d ^ ((i & 7) << 3))] = b;
  }
}

// ---------------- scan chunk body ----------------
__device__ __forceinline__ void scan_chunk(
    const char* CURB, char* OTHB, u16x4& VCUR, u16x4& VOTH, int CH,
    const char* scanA, const char* scanBg, const u16* vcrG, u16* coreB,
    float* sS, float* sVn, float* sVe,
    int nv, int h, int v0, int wave, int lane, int i2, int c4, int k5, int c8, int swi, int swk){
  // stage chunk+1 into OTHB (hidden under this chunk's compute)
  if (CH + 1 < 64){
    const char* gA = scanA + ((size_t)nv * 64 + CH + 1) * 25600;
    for (int slot = wave; slot < 25; slot += 4)
      gld16(gA + slot * 1024 + lane * 16, OTHB + slot * 1024);
    const char* gB2 = scanBg + ((size_t)h * 64 + CH + 1) * 32768;
    for (int slot = wave; slot < 32; slot += 4)
      gld16(gB2 + slot * 1024 + lane * 16, OTHB + 25600 + slot * 1024);
    VOTH = *(const u16x4*)&vcrG[((size_t)nv * 4096 + (CH + 1) * 64 + i2) * 128 + v0 + c4];
  }
  const u16* kcdL  = (const u16*)(CURB);
  const u16* attnL = (const u16*)(CURB + 16384);
  const float* egL = (const float*)(CURB + 24576);
  const u16* qL    = (const u16*)(CURB + 25600);
  const u16* ktL   = (const u16*)(CURB + 25600 + 16384);
  float eg_i = egL[i2], ed_i = egL[64 + i2], eL = egL[63];
  // v_prime = kcd @ S ; ai_raw = q @ S
  f32x4 vp = 0.f, ai = 0.f;
  for (int k = 0; k < 128; k += 4){
    f32x4 kf = b4f(*(const u16x4*)&kcdL[i2 * 128 + (k ^ swi)]);
    f32x4 qf = b4f(*(const u16x4*)&qL[i2 * 128 + (k ^ swi)]);
    #pragma unroll
    for (int kk = 0; kk < 4; kk++){
      f32x4 srow = *(const f32x4*)&sS[(k + kk) * 16 + c4];
      vp += kf[kk] * srow;
      ai += qf[kk] * srow;
    }
  }
  f32x4 vn = b4f(VCUR) - vp;
  *(f32x4*)&sVn[i2 * 16 + c4] = vn;
  *(f32x4*)&sVe[i2 * 16 + c4] = vn * ed_i;
  __syncthreads();
  // out = e^g * ai + attn_local @ v_new
  f32x4 o = ai * eg_i;
  for (int j = 0; j < 64; j += 4){
    f32x4 af = b4f(*(const u16x4*)&attnL[i2 * 64 + (j ^ swi)]);
    #pragma unroll
    for (int jj = 0; jj < 4; jj++)
      o += af[jj] * *(const f32x4*)&sVn[(j + jj) * 16 + c4];
  }
  { u16x4 ob; ob[0]=f2bf(o[0]); ob[1]=f2bf(o[1]); ob[2]=f2bf(o[2]); ob[3]=f2bf(o[3]);
    *(u16x4*)&coreB[(((size_t)(CH * 64 + i2)) * 32 + nv) * 128 + v0 + c4] = ob; }
  // S = S*eL + kT @ (v_new * e^d)
  f32x4 dla = 0.f, dlb = 0.f;
  for (int i = 0; i < 64; i += 8){
    u16x8 kb = *(const u16x8*)&ktL[k5 * 64 + (i ^ swk)];
    #pragma unroll
    for (int e = 0; e < 8; e++){
      float kv = bf2f(kb[e]);
      dla += kv * *(const f32x4*)&sVe[(i + e) * 16 + c8];
      dlb += kv * *(const f32x4*)&sVe[(i + e) * 16 + c8 + 4];
    }
  }
  { f32x4 sa = *(const f32x4*)&sS[k5 * 16 + c8];
    f32x4 sb = *(const f32x4*)&sS[k5 * 16 + c8 + 4];
    *(f32x4*)&sS[k5 * 16 + c8]     = sa * eL + dla;
    *(f32x4*)&sS[k5 * 16 + c8 + 4] = sb * eL + dlb; }
  __syncthreads();   // drains staging vmcnt + publishes sS
}

// ---------------- sequential inter-chunk scan; block = (nv, 16-col slice) ----------------
__global__ __launch_bounds__(256) void k_scan(const char* __restrict__ scanA, const char* __restrict__ scanBg,
    const u16* __restrict__ vcrG, u16* __restrict__ coreB){
  __shared__ alignas(16) char sbuf[2 * 58368];
  __shared__ float sS[2048];
  __shared__ float sVn[1024];
  __shared__ float sVe[1024];
  const int tid = threadIdx.x;
  const int wave = tid >> 6, lane = tid & 63;
  const int nv = blockIdx.x & 31, vg = blockIdx.x >> 5;
  const int h = nv >> 1, v0 = vg * 16;
  const int i2 = tid >> 2, c4 = (tid & 3) * 4;
  const int k5 = tid >> 1, c8 = (tid & 1) * 8;
  const int swi = (i2 & 7) << 3;
  const int swk = (k5 & 7) << 3;
  for (int t = tid; t < 2048; t += 256) sS[t] = 0.f;
  u16x4 vA, vB;
  {
    const char* gA = scanA + (size_t)(nv * 64) * 25600;
    for (int slot = wave; slot < 25; slot += 4)
      gld16(gA + slot * 1024 + lane * 16, sbuf + slot * 1024);
    const char* gB2 = scanBg + (size_t)(h * 64) * 32768;
    for (int slot = wave; slot < 32; slot += 4)
      gld16(gB2 + slot * 1024 + lane * 16, sbuf + 25600 + slot * 1024);
    vA = *(const u16x4*)&vcrG[((size_t)nv * 4096 + i2) * 128 + v0 + c4];
  }
  __syncthreads();
  for (int c = 0; c < 64; c += 2){
    scan_chunk(sbuf,         sbuf + 58368, vA, vB, c,
               scanA, scanBg, vcrG, coreB, sS, sVn, sVe,
               nv, h, v0, wave, lane, i2, c4, k5, c8, swi, swk);
    scan_chunk(sbuf + 58368, sbuf,         vB, vA, c + 1,
               scanA, scanBg, vcrG, coreB, sS, sVn, sVe,
               nv, h, v0, wave, lane, i2, c4, k5, c8, swi, swk);
  }
}

// ---------------- RMSNorm * norm_weight * silu(z) -> bf16 ----------------
__global__ __launch_bounds__(256) void k_gate(const u16* __restrict__ coreB, const u16* __restrict__ zB,
                                              const float* __restrict__ nw, u16* __restrict__ hb){
  int wave = threadIdx.x >> 6, lane = threadIdx.x & 63;
  int row = blockIdx.x * 4 + wave;    // s*32 + nv
  int s = row >> 5, nv = row & 31;
  u16x2 cu = *(const u16x2*)&coreB[(size_t)row * 128 + lane * 2];
  float c0 = bf2f(cu[0]), c1 = bf2f(cu[1]);
  float ss = c0 * c0 + c1 * c1;
  #pragma unroll
  for (int off = 32; off; off >>= 1) ss += __shfl_xor(ss, off);
  float rms = rsqrtf(ss * (1.f / 128.f) + 1e-6f);
  int zcol = (nv >> 1) * 256 + (nv & 1) * 128 + lane * 2;
  u16x2 zu = *(const u16x2*)&zB[(size_t)s * 4096 + zcol];
  float z0 = siluf(bf2f(zu[0])), z1 = siluf(bf2f(zu[1]));
  u16x2 ho;
  ho[0] = f2bf(c0 * rms * nw[lane * 2]     * z0);
  ho[1] = f2bf(c1 * rms * nw[lane * 2 + 1] * z1);
  *(u16x2*)&hb[(size_t)row * 128 + lane * 2] = ho;
}

extern "C" void kernel_launch(void* const* d_in, const int* in_sizes, int n_in,
                              void* d_out, int out_size, void* d_ws, size_t ws_size,
                              hipStream_t stream){
  (void)in_sizes; (void)n_in; (void)out_size; (void)ws_size;
  const float* hs    = (const float*)d_in[0];
  const float* Wqkvz = (const float*)d_in[1];
  const float* Wba   = (const float*)d_in[2];
  const float* cw    = (const float*)d_in[3];
  const float* dtb   = (const float*)d_in[4];
  const float* Alog  = (const float*)d_in[5];
  const float* nw    = (const float*)d_in[6];
  const float* Wout  = (const float*)d_in[7];
  char* ws = (char*)d_ws;
  const size_t MB = 1ull << 20;
  // 0-32MB:   hsb(0-16)+wqT head -> qcF f32 -> vcrG bf16 -> hb bf16
  // 16-64MB:  wqT -> vcB bf16 (32-64)
  // 64-128MB: qkvB -> scanA(64-114) + ba/betaB/gB(114-116)
  // 128-160:  zB
  // 160-192:  qcB(160-176)+kcB(176-192) -> coreB bf16
  // 192-224:  kcF f32 -> scanBg -> woT
  u16*   hsb   = (u16*)  (ws + 0);
  u16*   wqT   = (u16*)  (ws + 16 * MB);
  float* qcF   = (float*)(ws + 0);
  u16*   vcrG  = (u16*)  (ws + 0);
  u16*   hb    = (u16*)  (ws + 0);
  u16*   vcB   = (u16*)  (ws + 32 * MB);
  u16*   qkvB  = (u16*)  (ws + 64 * MB);
  char*  scanA =         (ws + 64 * MB);
  float* ba    = (float*)(ws + 114 * MB);
  float* betaB = (float*)(ws + 115 * MB);
  float* gB    = (float*)(ws + 115 * MB + 512 * 1024);
  u16*   zB    = (u16*)  (ws + 128 * MB);
  u16*   qcB   = (u16*)  (ws + 160 * MB);
  u16*   kcB   = (u16*)  (ws + 176 * MB);
  u16*   coreB = (u16*)  (ws + 160 * MB);
  float* kcF   = (float*)(ws + 192 * MB);
  char*  scanBg=         (ws + 192 * MB);
  u16*   woT   = (u16*)  (ws + 192 * MB);
  float* out   = (float*)d_out;

  k_cast<<<8192, 256, 0, stream>>>(hs, hsb, 2097152);
  k_trans<1><<<dim3(384, 64), dim3(32, 8), 0, stream>>>(Wqkvz, wqT, 2048, 12288);
  k_gemm<2><<<dim3(96, 32), 256, 0, stream>>>(hsb, wqT, qkvB, zB, 12288, 2048);
  k_conv<<<16384, 256, 0, stream>>>(qkvB, cw, qcF, kcF, vcB);
  k_ba<<<256, 256, 0, stream>>>(hs, Wba, ba);
  k_bg<<<512, 256, 0, stream>>>(ba, Alog, dtb, betaB, gB);
  k_rownorm<<<32768, 256, 0, stream>>>(qcF, kcF, qcB, kcB);
  k_pre<<<2048, 256, 0, stream>>>(qcB, kcB, vcB, betaB, gB, scanA, scanBg, vcrG);
  k_scan<<<256, 256, 0, stream>>>(scanA, scanBg, vcrG, coreB);
  k_gate<<<32768, 256, 0, stream>>>(coreB, zB, nw, hb);
  k_trans<0><<<dim3(64, 128), dim3(32, 8), 0, stream>>>(Wout, woT, 4096, 2048);
  k_gemm<0><<<dim3(16, 32), 256, 0, stream>>>(hb, woT, out, nullptr, 2048, 4096);
}

// Round 4
// 1368.773 us; speedup vs baseline: 1.4114x; 1.1983x over previous
//
#include <hip/hip_runtime.h>

typedef unsigned short u16;
typedef __attribute__((ext_vector_type(2))) float f32x2;
typedef __attribute__((ext_vector_type(4))) float f32x4;
typedef __attribute__((ext_vector_type(2))) u16 u16x2;
typedef __attribute__((ext_vector_type(4))) u16 u16x4;
typedef __attribute__((ext_vector_type(8))) u16 u16x8;
typedef __attribute__((ext_vector_type(8))) __bf16 bf16x8;

__device__ __forceinline__ float bf2f(u16 u){ unsigned v = ((unsigned)u) << 16; return __builtin_bit_cast(float, v); }
__device__ __forceinline__ u16 f2bf(float f){
  unsigned u = __builtin_bit_cast(unsigned, f);
  u += 0x7fffu + ((u >> 16) & 1u);
  return (u16)(u >> 16);
}
__device__ __forceinline__ f32x4 b4f(u16x4 u){
  f32x4 r; r[0] = bf2f(u[0]); r[1] = bf2f(u[1]); r[2] = bf2f(u[2]); r[3] = bf2f(u[3]); return r;
}
__device__ __forceinline__ u16x4 p4(f32x4 v){
  u16x4 o; o[0] = f2bf(v[0]); o[1] = f2bf(v[1]); o[2] = f2bf(v[2]); o[3] = f2bf(v[3]); return o;
}
__device__ __forceinline__ void gld16(const void* g, const void* l){
  __builtin_amdgcn_global_load_lds((__attribute__((address_space(1))) void*)(void*)g,
                                   (__attribute__((address_space(3))) void*)(void*)l, 16, 0, 0);
}
__device__ __forceinline__ float sigmoidf(float x){ return 1.f / (1.f + expf(-x)); }
__device__ __forceinline__ float siluf(float x){ return x / (1.f + expf(-x)); }

// ---------------- cast fp32 -> bf16 ----------------
__global__ __launch_bounds__(256) void k_cast(const float* __restrict__ in, u16* __restrict__ out, int n4){
  int t = blockIdx.x * 256 + threadIdx.x;
  if (t >= n4) return;
  f32x4 v = ((const f32x4*)in)[t];
  u16x4 o;
  o[0] = f2bf(v[0]); o[1] = f2bf(v[1]); o[2] = f2bf(v[2]); o[3] = f2bf(v[3]);
  ((u16x4*)out)[t] = o;
}

// ---------------- transpose + cast: in (K x N) f32 -> out (N x K) bf16 ----------------
template<int PERM>
__global__ __launch_bounds__(256) void k_trans(const float* __restrict__ in, u16* __restrict__ out, int K, int N){
  __shared__ float tile[32][33];
  int tx = threadIdx.x, ty = threadIdx.y;
  int n0 = blockIdx.x * 32, k0 = blockIdx.y * 32;
  #pragma unroll
  for (int j = 0; j < 32; j += 8) tile[ty + j][tx] = in[(size_t)(k0 + ty + j) * N + n0 + tx];
  __syncthreads();
  #pragma unroll
  for (int j = 0; j < 32; j += 8){
    int n = n0 + ty + j;
    int np;
    if (PERM){
      int g = n / 768, r = n - g * 768;
      np = (r < 512) ? (g * 512 + r) : (8192 + g * 256 + (r - 512));
    } else np = n;
    out[(size_t)np * K + k0 + tx] = f2bf(tile[tx][ty + j]);
  }
}

// ---------------- bf16 GEMM (m97 structure) ----------------
template<int MODE>
__global__ __launch_bounds__(256) void k_gemm(const u16* __restrict__ A, const u16* __restrict__ Bt,
                                              void* __restrict__ C, void* __restrict__ C2, int N, int K){
  __shared__ u16 As[128 * 32];
  __shared__ u16 Bs[128 * 32];
  const int tid = threadIdx.x;
  const int wave = tid >> 6, lane = tid & 63;
  const int gm = blockIdx.y * 128, gn = blockIdx.x * 128;
  const int c0 = wave * 2, c1 = c0 + 1;
  const int r0 = c0 * 16 + (lane >> 2), r1 = r0 + 16;
  const int kp = (lane & 3) * 8;
  const u16* a0 = A + (size_t)(gm + r0) * K + kp;
  const u16* a1 = A + (size_t)(gm + r1) * K + kp;
  const u16* b0 = Bt + (size_t)(gn + r0) * K + kp;
  const u16* b1 = Bt + (size_t)(gn + r1) * K + kp;
  const int wr = (wave >> 1) * 64, wc = (wave & 1) * 64;
  f32x4 acc[4][4];
  #pragma unroll
  for (int m = 0; m < 4; m++)
    #pragma unroll
    for (int n = 0; n < 4; n++) acc[m][n] = 0.f;
  for (int k0 = 0; k0 < K; k0 += 32){
    __syncthreads();
    gld16(a0 + k0, &As[c0 * 512]);
    gld16(a1 + k0, &As[c1 * 512]);
    gld16(b0 + k0, &Bs[c0 * 512]);
    gld16(b1 + k0, &Bs[c1 * 512]);
    __syncthreads();
    bf16x8 af[4], bfv[4];
    #pragma unroll
    for (int m = 0; m < 4; m++)
      af[m] = __builtin_bit_cast(bf16x8, *(const u16x8*)&As[(wr + m * 16 + (lane & 15)) * 32 + (lane >> 4) * 8]);
    #pragma unroll
    for (int n = 0; n < 4; n++)
      bfv[n] = __builtin_bit_cast(bf16x8, *(const u16x8*)&Bs[(wc + n * 16 + (lane & 15)) * 32 + (lane >> 4) * 8]);
    #pragma unroll
    for (int m = 0; m < 4; m++)
      #pragma unroll
      for (int n = 0; n < 4; n++)
        acc[m][n] = __builtin_amdgcn_mfma_f32_16x16x32_bf16(af[m], bfv[n], acc[m][n], 0, 0, 0);
  }
  #pragma unroll
  for (int m = 0; m < 4; m++){
    int row = gm + wr + m * 16 + (lane >> 4) * 4;
    #pragma unroll
    for (int n = 0; n < 4; n++){
      int col = gn + wc + n * 16 + (lane & 15);
      #pragma unroll
      for (int j = 0; j < 4; j++){
        if (MODE == 0){
          ((float*)C)[(size_t)(row + j) * N + col] = acc[m][n][j];
        } else {
          if (col < 8192) ((u16*)C)[(size_t)(row + j) * 8192 + col]         = f2bf(acc[m][n][j]);
          else            ((u16*)C2)[(size_t)(row + j) * 4096 + col - 8192] = f2bf(acc[m][n][j]);
        }
      }
    }
  }
}

// ---------------- small ba GEMM ----------------
__global__ __launch_bounds__(256) void k_ba(const float* __restrict__ hs, const float* __restrict__ Wba,
                                            float* __restrict__ ba){
  int wave = threadIdx.x >> 6, lane = threadIdx.x & 63;
  int s0 = (blockIdx.x * 4 + wave) * 4;
  f32x4 acc = 0.f;
  for (int k = 0; k < 2048; k += 4){
    float w0 = Wba[(size_t)(k + 0) * 64 + lane];
    float w1 = Wba[(size_t)(k + 1) * 64 + lane];
    float w2 = Wba[(size_t)(k + 2) * 64 + lane];
    float w3 = Wba[(size_t)(k + 3) * 64 + lane];
    f32x4 h0 = *(const f32x4*)&hs[(size_t)(s0 + 0) * 2048 + k];
    f32x4 h1 = *(const f32x4*)&hs[(size_t)(s0 + 1) * 2048 + k];
    f32x4 h2 = *(const f32x4*)&hs[(size_t)(s0 + 2) * 2048 + k];
    f32x4 h3 = *(const f32x4*)&hs[(size_t)(s0 + 3) * 2048 + k];
    acc[0] += h0[0]*w0 + h0[1]*w1 + h0[2]*w2 + h0[3]*w3;
    acc[1] += h1[0]*w0 + h1[1]*w1 + h1[2]*w2 + h1[3]*w3;
    acc[2] += h2[0]*w0 + h2[1]*w1 + h2[2]*w2 + h2[3]*w3;
    acc[3] += h3[0]*w0 + h3[1]*w1 + h3[2]*w2 + h3[3]*w3;
  }
  #pragma unroll
  for (int r = 0; r < 4; r++) ba[(size_t)(s0 + r) * 64 + lane] = acc[r];
}

// ---------------- causal dwconv(K=4)+SiLU; q/k -> f32, v -> bf16 ----------------
__global__ __launch_bounds__(256) void k_conv(const u16* __restrict__ qkvB, const float* __restrict__ cw,
                                              float* __restrict__ qcF, float* __restrict__ kcF, u16* __restrict__ vcB){
  int idx = blockIdx.x * 256 + threadIdx.x;      // 4096 * 1024
  int c8 = idx & 1023, s = idx >> 10;
  int c = c8 * 8;
  int col;
  if (c < 2048)      { int hh = c >> 7, d = c & 127; col = hh * 512 + d; }
  else if (c < 4096) { int cc = c - 2048, hh = cc >> 7, d = cc & 127; col = hh * 512 + 128 + d; }
  else               { int cc = c - 4096, nv = cc >> 7, d = cc & 127; col = (nv >> 1) * 512 + 256 + (nv & 1) * 128 + d; }
  float w[8][4];
  #pragma unroll
  for (int e = 0; e < 8; e++){
    f32x4 wv = *(const f32x4*)&cw[(size_t)(c + e) * 4];
    #pragma unroll
    for (int j = 0; j < 4; j++) w[e][j] = wv[j];
  }
  float acc[8] = {0.f,0.f,0.f,0.f,0.f,0.f,0.f,0.f};
  #pragma unroll
  for (int j = 0; j < 4; j++){
    int sp = s - 3 + j;
    if (sp < 0) continue;
    u16x8 x = *(const u16x8*)&qkvB[(size_t)sp * 8192 + col];
    #pragma unroll
    for (int e = 0; e < 8; e++) acc[e] += w[e][j] * bf2f(x[e]);
  }
  if (c < 4096){
    float* outp = (c < 2048) ? qcF + (size_t)s * 2048 + c : kcF + (size_t)s * 2048 + (c - 2048);
    f32x4 oa, ob;
    #pragma unroll
    for (int e = 0; e < 4; e++) oa[e] = siluf(acc[e]);
    #pragma unroll
    for (int e = 0; e < 4; e++) ob[e] = siluf(acc[e + 4]);
    *(f32x4*)&outp[0] = oa;
    *(f32x4*)&outp[4] = ob;
  } else {
    u16x8 ov;
    #pragma unroll
    for (int e = 0; e < 8; e++) ov[e] = f2bf(siluf(acc[e]));
    *(u16x8*)&vcB[(size_t)s * 4096 + (c - 4096)] = ov;
  }
}

// ---------------- beta / g ----------------
__global__ __launch_bounds__(256) void k_bg(const float* __restrict__ ba, const float* __restrict__ Alog,
                                            const float* __restrict__ dtb, float* __restrict__ betaO,
                                            float* __restrict__ gO){
  int idx = blockIdx.x * 256 + threadIdx.x;   // < 131072
  int s = idx >> 5, nv = idx & 31;
  float b = ba[(size_t)s * 64 + (nv >> 1) * 4 + (nv & 1)];
  float a = ba[(size_t)s * 64 + (nv >> 1) * 4 + 2 + (nv & 1)];
  betaO[idx] = sigmoidf(b);
  float x = a + dtb[nv];
  float sp = (x > 20.f) ? x : log1pf(expf(x));
  gO[idx] = -expf(Alog[nv]) * sp;
}

// ---------------- l2norm rows: f32 in -> bf16 out ----------------
__global__ __launch_bounds__(256) void k_rownorm(const float* __restrict__ qcF, const float* __restrict__ kcF,
                                                 u16* __restrict__ qcB, u16* __restrict__ kcB){
  int wave = threadIdx.x >> 6, lane = threadIdx.x & 63;
  int row = blockIdx.x * 4 + wave;  // first 65536 = q rows
  const float* src = (row < 65536) ? qcF + (size_t)row * 128 : kcF + (size_t)(row - 65536) * 128;
  u16* dst = (row < 65536) ? qcB + (size_t)row * 128 : kcB + (size_t)(row - 65536) * 128;
  float sc = (row < 65536) ? 0.08838834764831845f : 1.f;
  f32x2 v = ((const f32x2*)src)[lane];
  float ss = v[0] * v[0] + v[1] * v[1];
  #pragma unroll
  for (int off = 32; off; off >>= 1) ss += __shfl_xor(ss, off);
  float inv = rsqrtf(ss + 1e-6f) * sc;
  u16x2 o; o[0] = f2bf(v[0] * inv); o[1] = f2bf(v[1] * inv);
  ((u16x2*)dst)[lane] = o;
}

// ---------------- per-(nv,chunk) precompute; emits packed swizzled scan blocks ----------------
// scanA block (stride 25600B): [kcd 16KB swz | attn 8KB swz | eg 256B | ed 256B | pad]
// scanB block (stride 32768B, per (h,chunk), written by even nv): [q 16KB swz | kT 16KB swz]
// vcr block (stride 8192 u16 per (nv,chunk)): C-layout order [m4][vgrp8][lane64][j4]
__global__ __launch_bounds__(256) void k_pre(const u16* __restrict__ qcB, const u16* __restrict__ kcB,
    const u16* __restrict__ vcB, const float* __restrict__ betaB, const float* __restrict__ gB,
    char* __restrict__ scanA, char* __restrict__ scanBg, u16* __restrict__ vcrG){
  __shared__ float sK[64 * 132];
  __shared__ float sX[64 * 264];   // sQ aliases first part (disjoint lifetime)
  __shared__ float sM[64 * 68];
  __shared__ float sG[64];
  __shared__ float sEg[64];
  __shared__ float sBeta[64];
  float* sQ = sX;
  const int tid = threadIdx.x;
  const int nv = blockIdx.x & 31, chunk = blockIdx.x >> 5;
  const int h = nv >> 1, s0 = chunk * 64;
  char* gA = scanA + ((size_t)nv * 64 + chunk) * 25600;
  u16* kcdG = (u16*)gA;
  u16* attnG = (u16*)(gA + 16384);
  float* egG = (float*)(gA + 24576);
  char* gB2 = scanBg + ((size_t)h * 64 + chunk) * 32768;
  u16* qG  = (u16*)gB2;
  u16* ktG = (u16*)(gB2 + 16384);
  if (tid < 64){
    float g = gB[(size_t)(s0 + tid) * 32 + nv];
    #pragma unroll
    for (int off = 1; off < 64; off <<= 1){ float nb = __shfl_up(g, off); if (tid >= off) g += nb; }
    sG[tid] = g;
    float g63 = __shfl(g, 63);
    float eg = expf(g);
    sEg[tid] = eg;
    egG[tid] = eg;
    egG[64 + tid] = expf(g63 - g);
  } else if (tid < 128){
    sBeta[tid - 64] = betaB[(size_t)(s0 + tid - 64) * 32 + nv];
  }
  for (int t = tid; t < 2048; t += 256){
    int i = t >> 5, d = (t & 31) * 4;
    *(f32x4*)&sK[i * 132 + d] = b4f(*(const u16x4*)&kcB[(size_t)(s0 + i) * 2048 + h * 128 + d]);
    *(f32x4*)&sQ[i * 132 + d] = b4f(*(const u16x4*)&qcB[(size_t)(s0 + i) * 2048 + h * 128 + d]);
  }
  __syncthreads();
  // fused M (k_beta.k) and attn (q.k), 64x64x128
  const int jb = tid & 15, ib = tid >> 4;
  float mA[4][4] = {}, aA[4][4] = {};
  for (int k = 0; k < 128; k += 4){
    f32x4 kA[4], qA[4], kB[4];
    #pragma unroll
    for (int r = 0; r < 4; r++){
      kA[r] = *(const f32x4*)&sK[(ib * 4 + r) * 132 + k];
      qA[r] = *(const f32x4*)&sQ[(ib * 4 + r) * 132 + k];
      kB[r] = *(const f32x4*)&sK[(jb * 4 + r) * 132 + k];
    }
    #pragma unroll
    for (int r = 0; r < 4; r++)
      #pragma unroll
      for (int c2 = 0; c2 < 4; c2++)
        #pragma unroll
        for (int kk = 0; kk < 4; kk++){
          mA[r][c2] += kA[r][kk] * kB[c2][kk];
          aA[r][c2] += qA[r][kk] * kB[c2][kk];
        }
  }
  #pragma unroll
  for (int r = 0; r < 4; r++){
    int i = ib * 4 + r;
    float gi = sG[i], bi = sBeta[i];
    f32x4 mrow;
    u16x4 arow;
    #pragma unroll
    for (int c2 = 0; c2 < 4; c2++){
      int j = jb * 4 + c2;
      float dec = expf(gi - sG[j]);
      mrow[c2] = (i > j)  ? mA[r][c2] * bi * dec : 0.f;
      arow[c2] = f2bf((i >= j) ? aA[r][c2] * dec : 0.f);
    }
    *(f32x4*)&sM[i * 68 + jb * 4] = mrow;
    *(u16x4*)&attnG[i * 64 + ((jb * 4) ^ ((i & 7) << 3))] = arow;
  }
  // scanB outputs (one writer per h): raw q [i][k] swz, kT [k][i] swz
  if (!(nv & 1)){
    for (int t = tid; t < 2048; t += 256){
      int i = t >> 5, d = (t & 31) * 4;
      f32x4 qv = *(const f32x4*)&sQ[i * 132 + d];
      u16x4 o; o[0]=f2bf(qv[0]); o[1]=f2bf(qv[1]); o[2]=f2bf(qv[2]); o[3]=f2bf(qv[3]);
      *(u16x4*)&qG[i * 128 + (d ^ ((i & 7) << 3))] = o;
    }
    for (int t = tid; t < 2048; t += 256){
      int k = t & 127, i0 = (t >> 7) * 4;
      u16x4 o;
      #pragma unroll
      for (int r = 0; r < 4; r++) o[r] = f2bf(sK[(i0 + r) * 132 + k]);
      *(u16x4*)&ktG[k * 64 + (i0 ^ ((k & 7) << 3))] = o;
    }
  }
  __syncthreads();
  // X = [ v*beta | k*beta*exp(g) ]  (64 x 256), overwrites sQ region
  for (int t = tid; t < 2048; t += 256){
    int i = t >> 5, d = (t & 31) * 4;
    float bi = sBeta[i];
    f32x4 v = b4f(*(const u16x4*)&vcB[(size_t)(s0 + i) * 4096 + nv * 128 + d]);
    v *= bi;
    *(f32x4*)&sX[i * 264 + d] = v;
    f32x4 kb = *(const f32x4*)&sK[i * 132 + d];
    kb *= bi * sEg[i];
    *(f32x4*)&sX[i * 264 + 128 + d] = kb;
  }
  __syncthreads();
  // forward substitution; each thread owns one of 256 columns
  float x[64];
  #pragma unroll
  for (int i = 0; i < 64; i++) x[i] = sX[i * 264 + tid];
  #pragma unroll
  for (int i = 1; i < 64; i++){
    #pragma unroll
    for (int j = 0; j < i; j++) x[i] -= sM[i * 68 + j] * x[j];
  }
  #pragma unroll
  for (int i = 0; i < 64; i++) sX[i * 264 + tid] = x[i];
  __syncthreads();
  // kcd swizzled rows
  for (int t = tid; t < 2048; t += 256){
    int i = t >> 5, d = (t & 31) * 4;
    u16x4 b; b[0]=f2bf(sX[i*264+128+d]); b[1]=f2bf(sX[i*264+128+d+1]); b[2]=f2bf(sX[i*264+128+d+2]); b[3]=f2bf(sX[i*264+128+d+3]);
    *(u16x4*)&kcdG[i * 128 + (d ^ ((i & 7) << 3))] = b;
  }
  // vcr in scan C-layout order: [m][vgrp][lane=r*16+(v&15)][j]
  u16* vcrBlk = vcrG + ((size_t)nv * 64 + chunk) * 8192;
  for (int t = tid; t < 2048; t += 256){
    int vcol = t >> 4, m = (t >> 2) & 3, r = t & 3;
    int i0 = m * 16 + r * 4;
    u16x4 a;
    #pragma unroll
    for (int j = 0; j < 4; j++) a[j] = f2bf(sX[(i0 + j) * 264 + vcol]);
    *(u16x4*)&vcrBlk[(((m * 8 + (vcol >> 4)) * 64) + r * 16 + (vcol & 15)) * 4] = a;
  }
}

// ---------------- MFMA scan chunk body ----------------
__device__ __forceinline__ void scan_chunk(
    const char* CURB, char* OTHB, u16x4* VCUR, u16x4* VOTH, int CH,
    const char* scanA, const char* scanBg, const u16* vcrG, u16* coreB,
    u16* sST, u16* sVnT, u16* sVeT, f32x4* S,
    int nv, int h, int vg, int wave, int lane, int vgrp, int myv, int swv){
  const int vl = lane & 15, kg = lane >> 4;
  // prefetch staging for chunk+1 (drained by the end-of-chunk barrier)
  if (CH + 1 < 64){
    const char* gA = scanA + ((size_t)nv * 64 + CH + 1) * 25600;
    for (int slot = wave; slot < 25; slot += 4)
      gld16(gA + slot * 1024 + lane * 16, OTHB + slot * 1024);
    const char* gB2 = scanBg + ((size_t)h * 64 + CH + 1) * 32768;
    for (int slot = wave; slot < 32; slot += 4)
      gld16(gB2 + slot * 1024 + lane * 16, OTHB + 25600 + slot * 1024);
    const u16* vc = vcrG + ((size_t)nv * 64 + CH + 1) * 8192;
    #pragma unroll
    for (int m = 0; m < 4; m++)
      VOTH[m] = *(const u16x4*)&vc[((m * 8 + vgrp) * 64 + lane) * 4];
  }
  const u16* kcdL  = (const u16*)(CURB);
  const u16* attnL = (const u16*)(CURB + 16384);
  const float* egL = (const float*)(CURB + 24576);
  const u16* qL    = (const u16*)(CURB + 25600);
  const u16* ktL   = (const u16*)(CURB + 25600 + 16384);
  // vp = kcd @ S ; ai = q @ S   (B = sST rows own-wave)
  f32x4 vp[4], ai[4];
  #pragma unroll
  for (int m = 0; m < 4; m++){ vp[m] = 0.f; ai[m] = 0.f; }
  #pragma unroll
  for (int kt = 0; kt < 4; kt++){
    int ko = kt * 32 + kg * 8;
    bf16x8 sf = __builtin_bit_cast(bf16x8, *(const u16x8*)&sST[myv * 128 + (ko ^ swv)]);
    #pragma unroll
    for (int m = 0; m < 4; m++){
      int row = m * 16 + vl, rs = (row & 7) << 3;
      bf16x8 kf = __builtin_bit_cast(bf16x8, *(const u16x8*)&kcdL[row * 128 + (ko ^ rs)]);
      vp[m] = __builtin_amdgcn_mfma_f32_16x16x32_bf16(kf, sf, vp[m], 0, 0, 0);
      bf16x8 qf = __builtin_bit_cast(bf16x8, *(const u16x8*)&qL[row * 128 + (ko ^ rs)]);
      ai[m] = __builtin_amdgcn_mfma_f32_16x16x32_bf16(qf, sf, ai[m], 0, 0, 0);
    }
  }
  float eL = egL[63];
  #pragma unroll
  for (int m = 0; m < 4; m++){
    f32x4 vn = b4f(VCUR[m]) - vp[m];
    f32x4 ed4 = *(const f32x4*)&egL[64 + m * 16 + kg * 4];
    f32x4 eg4 = *(const f32x4*)&egL[m * 16 + kg * 4];
    int ja = (m * 16 + kg * 4) ^ swv;
    *(u16x4*)&sVnT[myv * 64 + ja] = p4(vn);
    *(u16x4*)&sVeT[myv * 64 + ja] = p4(vn * ed4);
    ai[m] *= eg4;
  }
  #pragma unroll
  for (int ms = 0; ms < 8; ms++) S[ms] *= eL;
  // out += attn_local @ vn ; S += kT @ vne   (B rows own-wave; no barrier needed)
  #pragma unroll
  for (int jt = 0; jt < 2; jt++){
    int jo = jt * 32 + kg * 8;
    bf16x8 vnf = __builtin_bit_cast(bf16x8, *(const u16x8*)&sVnT[myv * 64 + (jo ^ swv)]);
    bf16x8 vef = __builtin_bit_cast(bf16x8, *(const u16x8*)&sVeT[myv * 64 + (jo ^ swv)]);
    #pragma unroll
    for (int m = 0; m < 4; m++){
      int row = m * 16 + vl, rs = (row & 7) << 3;
      bf16x8 af = __builtin_bit_cast(bf16x8, *(const u16x8*)&attnL[row * 64 + (jo ^ rs)]);
      ai[m] = __builtin_amdgcn_mfma_f32_16x16x32_bf16(af, vnf, ai[m], 0, 0, 0);
    }
    #pragma unroll
    for (int ms = 0; ms < 8; ms++){
      int krow = ms * 16 + vl, rs = (krow & 7) << 3;
      bf16x8 kf = __builtin_bit_cast(bf16x8, *(const u16x8*)&ktL[krow * 64 + (jo ^ rs)]);
      S[ms] = __builtin_amdgcn_mfma_f32_16x16x32_bf16(kf, vef, S[ms], 0, 0, 0);
    }
  }
  // out store (C-layout: 4 rows i, fixed v per lane)
  #pragma unroll
  for (int m = 0; m < 4; m++){
    size_t ig = (size_t)CH * 64 + m * 16 + kg * 4;
    size_t base = (ig * 32 + nv) * 128 + vg * 64 + wave * 16 + vl;
    #pragma unroll
    for (int j = 0; j < 4; j++) coreB[base + (size_t)j * 4096] = f2bf(ai[m][j]);
  }
  // publish S^T (bf16) for next chunk's vp/ai
  #pragma unroll
  for (int ms = 0; ms < 8; ms++){
    int k0 = ms * 16 + kg * 4;
    *(u16x4*)&sST[myv * 128 + (k0 ^ swv)] = p4(S[ms]);
  }
  __syncthreads();
}

// ---------------- sequential inter-chunk scan; 64 blocks = 32 nv x 2 v-halves ----------------
__global__ __launch_bounds__(256) void k_scan(const char* __restrict__ scanA, const char* __restrict__ scanBg,
    const u16* __restrict__ vcrG, u16* __restrict__ coreB){
  __shared__ alignas(16) char sbuf[2 * 58368];
  __shared__ alignas(16) u16 sST[64 * 128];
  __shared__ alignas(16) u16 sVnT[64 * 64];
  __shared__ alignas(16) u16 sVeT[64 * 64];
  const int tid = threadIdx.x;
  const int wave = tid >> 6, lane = tid & 63;
  const int nv = blockIdx.x & 31, vg = blockIdx.x >> 5;
  const int h = nv >> 1;
  const int vgrp = vg * 4 + wave;
  const int myv = wave * 16 + (lane & 15);
  const int swv = (myv & 7) << 3;
  for (int t = tid; t < 8192; t += 256) sST[t] = 0;
  f32x4 S[8];
  #pragma unroll
  for (int ms = 0; ms < 8; ms++) S[ms] = 0.f;
  u16x4 vA[4], vB[4];
  {
    const char* gA = scanA + (size_t)(nv * 64) * 25600;
    for (int slot = wave; slot < 25; slot += 4)
      gld16(gA + slot * 1024 + lane * 16, sbuf + slot * 1024);
    const char* gB2 = scanBg + (size_t)(h * 64) * 32768;
    for (int slot = wave; slot < 32; slot += 4)
      gld16(gB2 + slot * 1024 + lane * 16, sbuf + 25600 + slot * 1024);
    const u16* vc = vcrG + (size_t)(nv * 64) * 8192;
    #pragma unroll
    for (int m = 0; m < 4; m++)
      vA[m] = *(const u16x4*)&vc[((m * 8 + vgrp) * 64 + lane) * 4];
  }
  __syncthreads();
  for (int c = 0; c < 64; c += 2){
    scan_chunk(sbuf,         sbuf + 58368, vA, vB, c,
               scanA, scanBg, vcrG, coreB, sST, sVnT, sVeT, S,
               nv, h, vg, wave, lane, vgrp, myv, swv);
    scan_chunk(sbuf + 58368, sbuf,         vB, vA, c + 1,
               scanA, scanBg, vcrG, coreB, sST, sVnT, sVeT, S,
               nv, h, vg, wave, lane, vgrp, myv, swv);
  }
}

// ---------------- RMSNorm * norm_weight * silu(z) -> bf16 ----------------
__global__ __launch_bounds__(256) void k_gate(const u16* __restrict__ coreB, const u16* __restrict__ zB,
                                              const float* __restrict__ nw, u16* __restrict__ hb){
  int wave = threadIdx.x >> 6, lane = threadIdx.x & 63;
  int row = blockIdx.x * 4 + wave;    // s*32 + nv
  int s = row >> 5, nv = row & 31;
  u16x2 cu = *(const u16x2*)&coreB[(size_t)row * 128 + lane * 2];
  float c0 = bf2f(cu[0]), c1 = bf2f(cu[1]);
  float ss = c0 * c0 + c1 * c1;
  #pragma unroll
  for (int off = 32; off; off >>= 1) ss += __shfl_xor(ss, off);
  float rms = rsqrtf(ss * (1.f / 128.f) + 1e-6f);
  int zcol = (nv >> 1) * 256 + (nv & 1) * 128 + lane * 2;
  u16x2 zu = *(const u16x2*)&zB[(size_t)s * 4096 + zcol];
  float z0 = siluf(bf2f(zu[0])), z1 = siluf(bf2f(zu[1]));
  u16x2 ho;
  ho[0] = f2bf(c0 * rms * nw[lane * 2]     * z0);
  ho[1] = f2bf(c1 * rms * nw[lane * 2 + 1] * z1);
  *(u16x2*)&hb[(size_t)row * 128 + lane * 2] = ho;
}

extern "C" void kernel_launch(void* const* d_in, const int* in_sizes, int n_in,
                              void* d_out, int out_size, void* d_ws, size_t ws_size,
                              hipStream_t stream){
  (void)in_sizes; (void)n_in; (void)out_size; (void)ws_size;
  const float* hs    = (const float*)d_in[0];
  const float* Wqkvz = (const float*)d_in[1];
  const float* Wba   = (const float*)d_in[2];
  const float* cw    = (const float*)d_in[3];
  const float* dtb   = (const float*)d_in[4];
  const float* Alog  = (const float*)d_in[5];
  const float* nw    = (const float*)d_in[6];
  const float* Wout  = (const float*)d_in[7];
  char* ws = (char*)d_ws;
  const size_t MB = 1ull << 20;
  u16*   hsb   = (u16*)  (ws + 0);
  u16*   wqT   = (u16*)  (ws + 16 * MB);
  float* qcF   = (float*)(ws + 0);
  u16*   vcrG  = (u16*)  (ws + 0);
  u16*   hb    = (u16*)  (ws + 0);
  u16*   vcB   = (u16*)  (ws + 32 * MB);
  u16*   qkvB  = (u16*)  (ws + 64 * MB);
  char*  scanA =         (ws + 64 * MB);
  float* ba    = (float*)(ws + 114 * MB);
  float* betaB = (float*)(ws + 115 * MB);
  float* gB    = (float*)(ws + 115 * MB + 512 * 1024);
  u16*   zB    = (u16*)  (ws + 128 * MB);
  u16*   qcB   = (u16*)  (ws + 160 * MB);
  u16*   kcB   = (u16*)  (ws + 176 * MB);
  u16*   coreB = (u16*)  (ws + 160 * MB);
  float* kcF   = (float*)(ws + 192 * MB);
  char*  scanBg=         (ws + 192 * MB);
  u16*   woT   = (u16*)  (ws + 192 * MB);
  float* out   = (float*)d_out;

  k_cast<<<8192, 256, 0, stream>>>(hs, hsb, 2097152);
  k_trans<1><<<dim3(384, 64), dim3(32, 8), 0, stream>>>(Wqkvz, wqT, 2048, 12288);
  k_gemm<2><<<dim3(96, 32), 256, 0, stream>>>(hsb, wqT, qkvB, zB, 12288, 2048);
  k_conv<<<16384, 256, 0, stream>>>(qkvB, cw, qcF, kcF, vcB);
  k_ba<<<256, 256, 0, stream>>>(hs, Wba, ba);
  k_bg<<<512, 256, 0, stream>>>(ba, Alog, dtb, betaB, gB);
  k_rownorm<<<32768, 256, 0, stream>>>(qcF, kcF, qcB, kcB);
  k_pre<<<2048, 256, 0, stream>>>(qcB, kcB, vcB, betaB, gB, scanA, scanBg, vcrG);
  k_scan<<<64, 256, 0, stream>>>(scanA, scanBg, vcrG, coreB);
  k_gate<<<32768, 256, 0, stream>>>(coreB, zB, nw, hb);
  k_trans<0><<<dim3(64, 128), dim3(32, 8), 0, stream>>>(Wout, woT, 4096, 2048);
  k_gemm<0><<<dim3(16, 32), 256, 0, stream>>>(hb, woT, out, nullptr, 2048, 4096);
}

// Round 5
// 1295.179 us; speedup vs baseline: 1.4916x; 1.0568x over previous
//
#include <hip/hip_runtime.h>

typedef unsigned short u16;
typedef __attribute__((ext_vector_type(2))) float f32x2;
typedef __attribute__((ext_vector_type(4))) float f32x4;
typedef __attribute__((ext_vector_type(2))) u16 u16x2;
typedef __attribute__((ext_vector_type(4))) u16 u16x4;
typedef __attribute__((ext_vector_type(8))) u16 u16x8;
typedef __attribute__((ext_vector_type(8))) __bf16 bf16x8;

__device__ __forceinline__ float bf2f(u16 u){ unsigned v = ((unsigned)u) << 16; return __builtin_bit_cast(float, v); }
__device__ __forceinline__ u16 f2bf(float f){
  unsigned u = __builtin_bit_cast(unsigned, f);
  u += 0x7fffu + ((u >> 16) & 1u);
  return (u16)(u >> 16);
}
__device__ __forceinline__ f32x4 b4f(u16x4 u){
  f32x4 r; r[0] = bf2f(u[0]); r[1] = bf2f(u[1]); r[2] = bf2f(u[2]); r[3] = bf2f(u[3]); return r;
}
__device__ __forceinline__ u16x4 p4(f32x4 v){
  u16x4 o; o[0] = f2bf(v[0]); o[1] = f2bf(v[1]); o[2] = f2bf(v[2]); o[3] = f2bf(v[3]); return o;
}
__device__ __forceinline__ void gld16(const void* g, const void* l){
  __builtin_amdgcn_global_load_lds((__attribute__((address_space(1))) void*)(void*)g,
                                   (__attribute__((address_space(3))) void*)(void*)l, 16, 0, 0);
}
__device__ __forceinline__ float sigmoidf(float x){ return 1.f / (1.f + expf(-x)); }
__device__ __forceinline__ float siluf(float x){ return x / (1.f + expf(-x)); }

#define GBAR() do { asm volatile("" ::: "memory"); __builtin_amdgcn_s_barrier(); asm volatile("" ::: "memory"); } while(0)

// ---------------- cast fp32 -> bf16 ----------------
__global__ __launch_bounds__(256) void k_cast(const float* __restrict__ in, u16* __restrict__ out, int n4){
  int t = blockIdx.x * 256 + threadIdx.x;
  if (t >= n4) return;
  f32x4 v = ((const f32x4*)in)[t];
  u16x4 o;
  o[0] = f2bf(v[0]); o[1] = f2bf(v[1]); o[2] = f2bf(v[2]); o[3] = f2bf(v[3]);
  ((u16x4*)out)[t] = o;
}

// ---------------- transpose + cast: in (K x N) f32 -> out (N x K) bf16 ----------------
template<int PERM>
__global__ __launch_bounds__(256) void k_trans(const float* __restrict__ in, u16* __restrict__ out, int K, int N){
  __shared__ float tile[32][33];
  int tx = threadIdx.x, ty = threadIdx.y;
  int n0 = blockIdx.x * 32, k0 = blockIdx.y * 32;
  #pragma unroll
  for (int j = 0; j < 32; j += 8) tile[ty + j][tx] = in[(size_t)(k0 + ty + j) * N + n0 + tx];
  __syncthreads();
  #pragma unroll
  for (int j = 0; j < 32; j += 8){
    int n = n0 + ty + j;
    int np;
    if (PERM){
      int g = n / 768, r = n - g * 768;
      np = (r < 512) ? (g * 512 + r) : (8192 + g * 256 + (r - 512));
    } else np = n;
    out[(size_t)np * K + k0 + tx] = f2bf(tile[tx][ty + j]);
  }
}

// ============ 256x256 8-phase pipelined bf16 GEMM (T1+T2+T3+T4+T5) ============
// A (M x K) rm bf16, Bt (N x K) rm bf16. 512 thr = 8 waves (2M x 4N), per-wave C 128x64.
// LDS: A,B each 2buf x 2half x (128 rows x 64 k) bf16, XOR-swizzled (row&7)<<4 on byte col.
// Stage stream: A1(t+1)@p1, B1(t+1)@p2, A0(t+2)@p3, B0(t+2)@p4 ; vmcnt(6)@p1, vmcnt(8)@p4.
template<int MODE>  // 0: f32 out ; 2: split bf16 out (col<8192 -> C w8192, else C2 w4096)
__global__ __launch_bounds__(512) void k_gemm256(const u16* __restrict__ A, const u16* __restrict__ Bt,
                                                 void* __restrict__ C, void* __restrict__ C2, int N, int K){
  __shared__ alignas(16) char lds[131072];
  const int tid = threadIdx.x;
  const int wid = tid >> 6, lane = tid & 63;
  const int vl = lane & 15, kg = lane >> 4;
  const int wm = wid >> 2, wn = wid & 3;
  const int nwg = (int)gridDim.x;
  const int swzb = ((int)blockIdx.x & 7) * (nwg >> 3) + ((int)blockIdx.x >> 3);
  const int nbx = N >> 8;
  const int bx = swzb % nbx, by = swzb / nbx;
  const int gm = by << 8, gn = bx << 8;
  const int nt = K >> 6;

  auto stageA = [&](int t, int h){
    if (t >= nt) return;
    const int k0 = t << 6;
    char* slot = lds + ((t & 1) * 2 + h) * 16384;
    #pragma unroll
    for (int p = 0; p < 2; p++){
      int o = p * 8192 + wid * 1024 + lane * 16;
      int sr = o >> 7, cs = (o >> 4) & 7;
      int gr = gm + ((sr >> 6) << 7) + h * 64 + (sr & 63);
      int gc = k0 + ((cs ^ (sr & 7)) << 3);
      gld16(A + (size_t)gr * K + gc, slot + p * 8192 + wid * 1024);
    }
  };
  auto stageB = [&](int t, int h){
    if (t >= nt) return;
    const int k0 = t << 6;
    char* slot = lds + 65536 + ((t & 1) * 2 + h) * 16384;
    #pragma unroll
    for (int p = 0; p < 2; p++){
      int o = p * 8192 + wid * 1024 + lane * 16;
      int sr = o >> 7, cs = (o >> 4) & 7;
      int gr = gn + ((sr >> 5) << 6) + h * 32 + (sr & 31);
      int gc = k0 + ((cs ^ (sr & 7)) << 3);
      gld16(Bt + (size_t)gr * K + gc, slot + p * 8192 + wid * 1024);
    }
  };

  f32x4 acc[8][4];
  #pragma unroll
  for (int a = 0; a < 8; a++)
    #pragma unroll
    for (int b = 0; b < 4; b++) acc[a][b] = 0.f;

  // prologue: A0(0) B0(0) A1(0) B1(0) A0(1) B0(1); drain the first tile's p1 halves
  stageA(0, 0); stageB(0, 0); stageA(0, 1); stageB(0, 1); stageA(1, 0); stageB(1, 0);
  asm volatile("s_waitcnt vmcnt(8)" ::: "memory");
  GBAR();

#define PHASE(MH, NH, STAGECALL, VMSEL) do { \
    const char* Asl_ = lds + ((cur * 2 + (MH)) * 16384); \
    const char* Bsl_ = lds + 65536 + ((cur * 2 + (NH)) * 16384); \
    bf16x8 af_[4][2], bf_[2][2]; \
    _Pragma("unroll") \
    for (int mi = 0; mi < 4; mi++){ \
      int sr = wm * 64 + mi * 16 + vl; \
      _Pragma("unroll") \
      for (int ks = 0; ks < 2; ks++) \
        af_[mi][ks] = __builtin_bit_cast(bf16x8, *(const u16x8*)(Asl_ + sr * 128 + (((ks * 4 + kg) ^ (vl & 7)) << 4))); \
    } \
    _Pragma("unroll") \
    for (int ni = 0; ni < 2; ni++){ \
      int br = wn * 32 + ni * 16 + vl; \
      _Pragma("unroll") \
      for (int ks = 0; ks < 2; ks++) \
        bf_[ni][ks] = __builtin_bit_cast(bf16x8, *(const u16x8*)(Bsl_ + br * 128 + (((ks * 4 + kg) ^ (vl & 7)) << 4))); \
    } \
    STAGECALL; \
    __builtin_amdgcn_s_setprio(1); \
    _Pragma("unroll") \
    for (int mi = 0; mi < 4; mi++) \
      _Pragma("unroll") \
      for (int ni = 0; ni < 2; ni++) \
        _Pragma("unroll") \
        for (int ks = 0; ks < 2; ks++) \
          acc[(MH) * 4 + mi][(NH) * 2 + ni] = __builtin_amdgcn_mfma_f32_16x16x32_bf16(af_[mi][ks], bf_[ni][ks], acc[(MH) * 4 + mi][(NH) * 2 + ni], 0, 0, 0); \
    __builtin_amdgcn_s_setprio(0); \
    VMSEL; \
    GBAR(); \
  } while (0)

  for (int t = 0; t < nt; t++){
    const int cur = t & 1;
    const bool tail = (t >= nt - 3);
    PHASE(0, 0, stageA(t + 1, 1),
          { if (!tail) asm volatile("s_waitcnt vmcnt(6)" ::: "memory");
            else       asm volatile("s_waitcnt vmcnt(0)" ::: "memory"); });
    PHASE(0, 1, stageB(t + 1, 1), {});
    PHASE(1, 0, stageA(t + 2, 0), {});
    PHASE(1, 1, stageB(t + 2, 0),
          { if (!tail) asm volatile("s_waitcnt vmcnt(8)" ::: "memory");
            else       asm volatile("s_waitcnt vmcnt(0)" ::: "memory"); });
  }
#undef PHASE

  #pragma unroll
  for (int a = 0; a < 8; a++){
    int row = gm + wm * 128 + (a >> 2) * 64 + (a & 3) * 16 + (lane >> 4) * 4;
    #pragma unroll
    for (int b = 0; b < 4; b++){
      int col = gn + wn * 64 + (b >> 1) * 32 + (b & 1) * 16 + vl;
      #pragma unroll
      for (int j = 0; j < 4; j++){
        if (MODE == 0){
          ((float*)C)[(size_t)(row + j) * N + col] = acc[a][b][j];
        } else {
          if (col < 8192) ((u16*)C)[(size_t)(row + j) * 8192 + col]         = f2bf(acc[a][b][j]);
          else            ((u16*)C2)[(size_t)(row + j) * 4096 + col - 8192] = f2bf(acc[a][b][j]);
        }
      }
    }
  }
}

// ---------------- bf16 GEMM (m97 structure, + XCD swizzle) — used for GEMM2 ----------------
template<int MODE>
__global__ __launch_bounds__(256) void k_gemm(const u16* __restrict__ A, const u16* __restrict__ Bt,
                                              void* __restrict__ C, void* __restrict__ C2, int N, int K){
  __shared__ u16 As[128 * 32];
  __shared__ u16 Bs[128 * 32];
  const int tid = threadIdx.x;
  const int wave = tid >> 6, lane = tid & 63;
  const int nbx = (int)gridDim.x;
  const int nwg = nbx * (int)gridDim.y;
  const int linear = (int)blockIdx.y * nbx + (int)blockIdx.x;
  const int swz = (linear & 7) * (nwg >> 3) + (linear >> 3);
  const int gm = (swz / nbx) * 128, gn = (swz % nbx) * 128;
  const int c0 = wave * 2, c1 = c0 + 1;
  const int r0 = c0 * 16 + (lane >> 2), r1 = r0 + 16;
  const int kp = (lane & 3) * 8;
  const u16* a0 = A + (size_t)(gm + r0) * K + kp;
  const u16* a1 = A + (size_t)(gm + r1) * K + kp;
  const u16* b0 = Bt + (size_t)(gn + r0) * K + kp;
  const u16* b1 = Bt + (size_t)(gn + r1) * K + kp;
  const int wr = (wave >> 1) * 64, wc = (wave & 1) * 64;
  f32x4 acc[4][4];
  #pragma unroll
  for (int m = 0; m < 4; m++)
    #pragma unroll
    for (int n = 0; n < 4; n++) acc[m][n] = 0.f;
  for (int k0 = 0; k0 < K; k0 += 32){
    __syncthreads();
    gld16(a0 + k0, &As[c0 * 512]);
    gld16(a1 + k0, &As[c1 * 512]);
    gld16(b0 + k0, &Bs[c0 * 512]);
    gld16(b1 + k0, &Bs[c1 * 512]);
    __syncthreads();
    bf16x8 af[4], bfv[4];
    #pragma unroll
    for (int m = 0; m < 4; m++)
      af[m] = __builtin_bit_cast(bf16x8, *(const u16x8*)&As[(wr + m * 16 + (lane & 15)) * 32 + (lane >> 4) * 8]);
    #pragma unroll
    for (int n = 0; n < 4; n++)
      bfv[n] = __builtin_bit_cast(bf16x8, *(const u16x8*)&Bs[(wc + n * 16 + (lane & 15)) * 32 + (lane >> 4) * 8]);
    #pragma unroll
    for (int m = 0; m < 4; m++)
      #pragma unroll
      for (int n = 0; n < 4; n++)
        acc[m][n] = __builtin_amdgcn_mfma_f32_16x16x32_bf16(af[m], bfv[n], acc[m][n], 0, 0, 0);
  }
  #pragma unroll
  for (int m = 0; m < 4; m++){
    int row = gm + wr + m * 16 + (lane >> 4) * 4;
    #pragma unroll
    for (int n = 0; n < 4; n++){
      int col = gn + wc + n * 16 + (lane & 15);
      #pragma unroll
      for (int j = 0; j < 4; j++){
        if (MODE == 0){
          ((float*)C)[(size_t)(row + j) * N + col] = acc[m][n][j];
        } else {
          if (col < 8192) ((u16*)C)[(size_t)(row + j) * 8192 + col]         = f2bf(acc[m][n][j]);
          else            ((u16*)C2)[(size_t)(row + j) * 4096 + col - 8192] = f2bf(acc[m][n][j]);
        }
      }
    }
  }
}

// ---------------- small ba GEMM ----------------
__global__ __launch_bounds__(256) void k_ba(const float* __restrict__ hs, const float* __restrict__ Wba,
                                            float* __restrict__ ba){
  int wave = threadIdx.x >> 6, lane = threadIdx.x & 63;
  int s0 = (blockIdx.x * 4 + wave) * 4;
  f32x4 acc = 0.f;
  for (int k = 0; k < 2048; k += 4){
    float w0 = Wba[(size_t)(k + 0) * 64 + lane];
    float w1 = Wba[(size_t)(k + 1) * 64 + lane];
    float w2 = Wba[(size_t)(k + 2) * 64 + lane];
    float w3 = Wba[(size_t)(k + 3) * 64 + lane];
    f32x4 h0 = *(const f32x4*)&hs[(size_t)(s0 + 0) * 2048 + k];
    f32x4 h1 = *(const f32x4*)&hs[(size_t)(s0 + 1) * 2048 + k];
    f32x4 h2 = *(const f32x4*)&hs[(size_t)(s0 + 2) * 2048 + k];
    f32x4 h3 = *(const f32x4*)&hs[(size_t)(s0 + 3) * 2048 + k];
    acc[0] += h0[0]*w0 + h0[1]*w1 + h0[2]*w2 + h0[3]*w3;
    acc[1] += h1[0]*w0 + h1[1]*w1 + h1[2]*w2 + h1[3]*w3;
    acc[2] += h2[0]*w0 + h2[1]*w1 + h2[2]*w2 + h2[3]*w3;
    acc[3] += h3[0]*w0 + h3[1]*w1 + h3[2]*w2 + h3[3]*w3;
  }
  #pragma unroll
  for (int r = 0; r < 4; r++) ba[(size_t)(s0 + r) * 64 + lane] = acc[r];
}

// ---------------- causal dwconv(K=4)+SiLU; q/k -> f32, v -> bf16 ----------------
__global__ __launch_bounds__(256) void k_conv(const u16* __restrict__ qkvB, const float* __restrict__ cw,
                                              float* __restrict__ qcF, float* __restrict__ kcF, u16* __restrict__ vcB){
  int idx = blockIdx.x * 256 + threadIdx.x;      // 4096 * 1024
  int c8 = idx & 1023, s = idx >> 10;
  int c = c8 * 8;
  int col;
  if (c < 2048)      { int hh = c >> 7, d = c & 127; col = hh * 512 + d; }
  else if (c < 4096) { int cc = c - 2048, hh = cc >> 7, d = cc & 127; col = hh * 512 + 128 + d; }
  else               { int cc = c - 4096, nv = cc >> 7, d = cc & 127; col = (nv >> 1) * 512 + 256 + (nv & 1) * 128 + d; }
  float w[8][4];
  #pragma unroll
  for (int e = 0; e < 8; e++){
    f32x4 wv = *(const f32x4*)&cw[(size_t)(c + e) * 4];
    #pragma unroll
    for (int j = 0; j < 4; j++) w[e][j] = wv[j];
  }
  float acc[8] = {0.f,0.f,0.f,0.f,0.f,0.f,0.f,0.f};
  #pragma unroll
  for (int j = 0; j < 4; j++){
    int sp = s - 3 + j;
    if (sp < 0) continue;
    u16x8 x = *(const u16x8*)&qkvB[(size_t)sp * 8192 + col];
    #pragma unroll
    for (int e = 0; e < 8; e++) acc[e] += w[e][j] * bf2f(x[e]);
  }
  if (c < 4096){
    float* outp = (c < 2048) ? qcF + (size_t)s * 2048 + c : kcF + (size_t)s * 2048 + (c - 2048);
    f32x4 oa, ob;
    #pragma unroll
    for (int e = 0; e < 4; e++) oa[e] = siluf(acc[e]);
    #pragma unroll
    for (int e = 0; e < 4; e++) ob[e] = siluf(acc[e + 4]);
    *(f32x4*)&outp[0] = oa;
    *(f32x4*)&outp[4] = ob;
  } else {
    u16x8 ov;
    #pragma unroll
    for (int e = 0; e < 8; e++) ov[e] = f2bf(siluf(acc[e]));
    *(u16x8*)&vcB[(size_t)s * 4096 + (c - 4096)] = ov;
  }
}

// ---------------- beta / g ----------------
__global__ __launch_bounds__(256) void k_bg(const float* __restrict__ ba, const float* __restrict__ Alog,
                                            const float* __restrict__ dtb, float* __restrict__ betaO,
                                            float* __restrict__ gO){
  int idx = blockIdx.x * 256 + threadIdx.x;   // < 131072
  int s = idx >> 5, nv = idx & 31;
  float b = ba[(size_t)s * 64 + (nv >> 1) * 4 + (nv & 1)];
  float a = ba[(size_t)s * 64 + (nv >> 1) * 4 + 2 + (nv & 1)];
  betaO[idx] = sigmoidf(b);
  float x = a + dtb[nv];
  float sp = (x > 20.f) ? x : log1pf(expf(x));
  gO[idx] = -expf(Alog[nv]) * sp;
}

// ---------------- l2norm rows: f32 in -> bf16 out ----------------
__global__ __launch_bounds__(256) void k_rownorm(const float* __restrict__ qcF, const float* __restrict__ kcF,
                                                 u16* __restrict__ qcB, u16* __restrict__ kcB){
  int wave = threadIdx.x >> 6, lane = threadIdx.x & 63;
  int row = blockIdx.x * 4 + wave;  // first 65536 = q rows
  const float* src = (row < 65536) ? qcF + (size_t)row * 128 : kcF + (size_t)(row - 65536) * 128;
  u16* dst = (row < 65536) ? qcB + (size_t)row * 128 : kcB + (size_t)(row - 65536) * 128;
  float sc = (row < 65536) ? 0.08838834764831845f : 1.f;
  f32x2 v = ((const f32x2*)src)[lane];
  float ss = v[0] * v[0] + v[1] * v[1];
  #pragma unroll
  for (int off = 32; off; off >>= 1) ss += __shfl_xor(ss, off);
  float inv = rsqrtf(ss + 1e-6f) * sc;
  u16x2 o; o[0] = f2bf(v[0] * inv); o[1] = f2bf(v[1] * inv);
  ((u16x2*)dst)[lane] = o;
}

// ---------------- per-(nv,chunk) precompute; emits packed swizzled scan blocks ----------------
__global__ __launch_bounds__(256) void k_pre(const u16* __restrict__ qcB, const u16* __restrict__ kcB,
    const u16* __restrict__ vcB, const float* __restrict__ betaB, const float* __restrict__ gB,
    char* __restrict__ scanA, char* __restrict__ scanBg, u16* __restrict__ vcrG){
  __shared__ float sK[64 * 132];
  __shared__ float sX[64 * 264];   // sQ aliases first part (disjoint lifetime)
  __shared__ float sM[64 * 68];
  __shared__ float sG[64];
  __shared__ float sEg[64];
  __shared__ float sBeta[64];
  float* sQ = sX;
  const int tid = threadIdx.x;
  const int nv = blockIdx.x & 31, chunk = blockIdx.x >> 5;
  const int h = nv >> 1, s0 = chunk * 64;
  char* gA = scanA + ((size_t)nv * 64 + chunk) * 25600;
  u16* kcdG = (u16*)gA;
  u16* attnG = (u16*)(gA + 16384);
  float* egG = (float*)(gA + 24576);
  char* gB2 = scanBg + ((size_t)h * 64 + chunk) * 32768;
  u16* qG  = (u16*)gB2;
  u16* ktG = (u16*)(gB2 + 16384);
  if (tid < 64){
    float g = gB[(size_t)(s0 + tid) * 32 + nv];
    #pragma unroll
    for (int off = 1; off < 64; off <<= 1){ float nb = __shfl_up(g, off); if (tid >= off) g += nb; }
    sG[tid] = g;
    float g63 = __shfl(g, 63);
    float eg = expf(g);
    sEg[tid] = eg;
    egG[tid] = eg;
    egG[64 + tid] = expf(g63 - g);
  } else if (tid < 128){
    sBeta[tid - 64] = betaB[(size_t)(s0 + tid - 64) * 32 + nv];
  }
  for (int t = tid; t < 2048; t += 256){
    int i = t >> 5, d = (t & 31) * 4;
    *(f32x4*)&sK[i * 132 + d] = b4f(*(const u16x4*)&kcB[(size_t)(s0 + i) * 2048 + h * 128 + d]);
    *(f32x4*)&sQ[i * 132 + d] = b4f(*(const u16x4*)&qcB[(size_t)(s0 + i) * 2048 + h * 128 + d]);
  }
  __syncthreads();
  const int jb = tid & 15, ib = tid >> 4;
  float mA[4][4] = {}, aA[4][4] = {};
  for (int k = 0; k < 128; k += 4){
    f32x4 kA[4], qA[4], kB[4];
    #pragma unroll
    for (int r = 0; r < 4; r++){
      kA[r] = *(const f32x4*)&sK[(ib * 4 + r) * 132 + k];
      qA[r] = *(const f32x4*)&sQ[(ib * 4 + r) * 132 + k];
      kB[r] = *(const f32x4*)&sK[(jb * 4 + r) * 132 + k];
    }
    #pragma unroll
    for (int r = 0; r < 4; r++)
      #pragma unroll
      for (int c2 = 0; c2 < 4; c2++)
        #pragma unroll
        for (int kk = 0; kk < 4; kk++){
          mA[r][c2] += kA[r][kk] * kB[c2][kk];
          aA[r][c2] += qA[r][kk] * kB[c2][kk];
        }
  }
  #pragma unroll
  for (int r = 0; r < 4; r++){
    int i = ib * 4 + r;
    float gi = sG[i], bi = sBeta[i];
    f32x4 mrow;
    u16x4 arow;
    #pragma unroll
    for (int c2 = 0; c2 < 4; c2++){
      int j = jb * 4 + c2;
      float dec = expf(gi - sG[j]);
      mrow[c2] = (i > j)  ? mA[r][c2] * bi * dec : 0.f;
      arow[c2] = f2bf((i >= j) ? aA[r][c2] * dec : 0.f);
    }
    *(f32x4*)&sM[i * 68 + jb * 4] = mrow;
    *(u16x4*)&attnG[i * 64 + ((jb * 4) ^ ((i & 7) << 3))] = arow;
  }
  if (!(nv & 1)){
    for (int t = tid; t < 2048; t += 256){
      int i = t >> 5, d = (t & 31) * 4;
      f32x4 qv = *(const f32x4*)&sQ[i * 132 + d];
      u16x4 o; o[0]=f2bf(qv[0]); o[1]=f2bf(qv[1]); o[2]=f2bf(qv[2]); o[3]=f2bf(qv[3]);
      *(u16x4*)&qG[i * 128 + (d ^ ((i & 7) << 3))] = o;
    }
    for (int t = tid; t < 2048; t += 256){
      int k = t & 127, i0 = (t >> 7) * 4;
      u16x4 o;
      #pragma unroll
      for (int r = 0; r < 4; r++) o[r] = f2bf(sK[(i0 + r) * 132 + k]);
      *(u16x4*)&ktG[k * 64 + (i0 ^ ((k & 7) << 3))] = o;
    }
  }
  __syncthreads();
  for (int t = tid; t < 2048; t += 256){
    int i = t >> 5, d = (t & 31) * 4;
    float bi = sBeta[i];
    f32x4 v = b4f(*(const u16x4*)&vcB[(size_t)(s0 + i) * 4096 + nv * 128 + d]);
    v *= bi;
    *(f32x4*)&sX[i * 264 + d] = v;
    f32x4 kb = *(const f32x4*)&sK[i * 132 + d];
    kb *= bi * sEg[i];
    *(f32x4*)&sX[i * 264 + 128 + d] = kb;
  }
  __syncthreads();
  float x[64];
  #pragma unroll
  for (int i = 0; i < 64; i++) x[i] = sX[i * 264 + tid];
  #pragma unroll
  for (int i = 1; i < 64; i++){
    #pragma unroll
    for (int j = 0; j < i; j++) x[i] -= sM[i * 68 + j] * x[j];
  }
  #pragma unroll
  for (int i = 0; i < 64; i++) sX[i * 264 + tid] = x[i];
  __syncthreads();
  for (int t = tid; t < 2048; t += 256){
    int i = t >> 5, d = (t & 31) * 4;
    u16x4 b; b[0]=f2bf(sX[i*264+128+d]); b[1]=f2bf(sX[i*264+128+d+1]); b[2]=f2bf(sX[i*264+128+d+2]); b[3]=f2bf(sX[i*264+128+d+3]);
    *(u16x4*)&kcdG[i * 128 + (d ^ ((i & 7) << 3))] = b;
  }
  u16* vcrBlk = vcrG + ((size_t)nv * 64 + chunk) * 8192;
  for (int t = tid; t < 2048; t += 256){
    int vcol = t >> 4, m = (t >> 2) & 3, r = t & 3;
    int i0 = m * 16 + r * 4;
    u16x4 a;
    #pragma unroll
    for (int j = 0; j < 4; j++) a[j] = f2bf(sX[(i0 + j) * 264 + vcol]);
    *(u16x4*)&vcrBlk[(((m * 8 + (vcol >> 4)) * 64) + r * 16 + (vcol & 15)) * 4] = a;
  }
}

// ---------------- MFMA scan chunk body ----------------
__device__ __forceinline__ void scan_chunk(
    const char* CURB, char* OTHB, u16x4* VCUR, u16x4* VOTH, int CH,
    const char* scanA, const char* scanBg, const u16* vcrG, u16* coreB,
    u16* sST, u16* sVnT, u16* sVeT, f32x4* S,
    int nv, int h, int vg, int wave, int lane, int vgrp, int myv, int swv){
  const int vl = lane & 15, kg = lane >> 4;
  if (CH + 1 < 64){
    const char* gA = scanA + ((size_t)nv * 64 + CH + 1) * 25600;
    for (int slot = wave; slot < 25; slot += 4)
      gld16(gA + slot * 1024 + lane * 16, OTHB + slot * 1024);
    const char* gB2 = scanBg + ((size_t)h * 64 + CH + 1) * 32768;
    for (int slot = wave; slot < 32; slot += 4)
      gld16(gB2 + slot * 1024 + lane * 16, OTHB + 25600 + slot * 1024);
    const u16* vc = vcrG + ((size_t)nv * 64 + CH + 1) * 8192;
    #pragma unroll
    for (int m = 0; m < 4; m++)
      VOTH[m] = *(const u16x4*)&vc[((m * 8 + vgrp) * 64 + lane) * 4];
  }
  const u16* kcdL  = (const u16*)(CURB);
  const u16* attnL = (const u16*)(CURB + 16384);
  const float* egL = (const float*)(CURB + 24576);
  const u16* qL    = (const u16*)(CURB + 25600);
  const u16* ktL   = (const u16*)(CURB + 25600 + 16384);
  f32x4 vp[4], ai[4];
  #pragma unroll
  for (int m = 0; m < 4; m++){ vp[m] = 0.f; ai[m] = 0.f; }
  #pragma unroll
  for (int kt = 0; kt < 4; kt++){
    int ko = kt * 32 + kg * 8;
    bf16x8 sf = __builtin_bit_cast(bf16x8, *(const u16x8*)&sST[myv * 128 + (ko ^ swv)]);
    #pragma unroll
    for (int m = 0; m < 4; m++){
      int row = m * 16 + vl, rs = (row & 7) << 3;
      bf16x8 kf = __builtin_bit_cast(bf16x8, *(const u16x8*)&kcdL[row * 128 + (ko ^ rs)]);
      vp[m] = __builtin_amdgcn_mfma_f32_16x16x32_bf16(kf, sf, vp[m], 0, 0, 0);
      bf16x8 qf = __builtin_bit_cast(bf16x8, *(const u16x8*)&qL[row * 128 + (ko ^ rs)]);
      ai[m] = __builtin_amdgcn_mfma_f32_16x16x32_bf16(qf, sf, ai[m], 0, 0, 0);
    }
  }
  float eL = egL[63];
  #pragma unroll
  for (int m = 0; m < 4; m++){
    f32x4 vn = b4f(VCUR[m]) - vp[m];
    f32x4 ed4 = *(const f32x4*)&egL[64 + m * 16 + kg * 4];
    f32x4 eg4 = *(const f32x4*)&egL[m * 16 + kg * 4];
    int ja = (m * 16 + kg * 4) ^ swv;
    *(u16x4*)&sVnT[myv * 64 + ja] = p4(vn);
    *(u16x4*)&sVeT[myv * 64 + ja] = p4(vn * ed4);
    ai[m] *= eg4;
  }
  #pragma unroll
  for (int ms = 0; ms < 8; ms++) S[ms] *= eL;
  #pragma unroll
  for (int jt = 0; jt < 2; jt++){
    int jo = jt * 32 + kg * 8;
    bf16x8 vnf = __builtin_bit_cast(bf16x8, *(const u16x8*)&sVnT[myv * 64 + (jo ^ swv)]);
    bf16x8 vef = __builtin_bit_cast(bf16x8, *(const u16x8*)&sVeT[myv * 64 + (jo ^ swv)]);
    #pragma unroll
    for (int m = 0; m < 4; m++){
      int row = m * 16 + vl, rs = (row & 7) << 3;
      bf16x8 af = __builtin_bit_cast(bf16x8, *(const u16x8*)&attnL[row * 64 + (jo ^ rs)]);
      ai[m] = __builtin_amdgcn_mfma_f32_16x16x32_bf16(af, vnf, ai[m], 0, 0, 0);
    }
    #pragma unroll
    for (int ms = 0; ms < 8; ms++){
      int krow = ms * 16 + vl, rs = (krow & 7) << 3;
      bf16x8 kf = __builtin_bit_cast(bf16x8, *(const u16x8*)&ktL[krow * 64 + (jo ^ rs)]);
      S[ms] = __builtin_amdgcn_mfma_f32_16x16x32_bf16(kf, vef, S[ms], 0, 0, 0);
    }
  }
  #pragma unroll
  for (int m = 0; m < 4; m++){
    size_t ig = (size_t)CH * 64 + m * 16 + kg * 4;
    size_t base = (ig * 32 + nv) * 128 + vg * 64 + wave * 16 + vl;
    #pragma unroll
    for (int j = 0; j < 4; j++) coreB[base + (size_t)j * 4096] = f2bf(ai[m][j]);
  }
  #pragma unroll
  for (int ms = 0; ms < 8; ms++){
    int k0 = ms * 16 + kg * 4;
    *(u16x4*)&sST[myv * 128 + (k0 ^ swv)] = p4(S[ms]);
  }
  __syncthreads();
}

// ---------------- sequential inter-chunk scan; 64 blocks = 32 nv x 2 v-halves ----------------
__global__ __launch_bounds__(256) void k_scan(const char* __restrict__ scanA, const char* __restrict__ scanBg,
    const u16* __restrict__ vcrG, u16* __restrict__ coreB){
  __shared__ alignas(16) char sbuf[2 * 58368];
  __shared__ alignas(16) u16 sST[64 * 128];
  __shared__ alignas(16) u16 sVnT[64 * 64];
  __shared__ alignas(16) u16 sVeT[64 * 64];
  const int tid = threadIdx.x;
  const int wave = tid >> 6, lane = tid & 63;
  const int nv = blockIdx.x & 31, vg = blockIdx.x >> 5;
  const int h = nv >> 1;
  const int vgrp = vg * 4 + wave;
  const int myv = wave * 16 + (lane & 15);
  const int swv = (myv & 7) << 3;
  for (int t = tid; t < 8192; t += 256) sST[t] = 0;
  f32x4 S[8];
  #pragma unroll
  for (int ms = 0; ms < 8; ms++) S[ms] = 0.f;
  u16x4 vA[4], vB[4];
  {
    const char* gA = scanA + (size_t)(nv * 64) * 25600;
    for (int slot = wave; slot < 25; slot += 4)
      gld16(gA + slot * 1024 + lane * 16, sbuf + slot * 1024);
    const char* gB2 = scanBg + (size_t)(h * 64) * 32768;
    for (int slot = wave; slot < 32; slot += 4)
      gld16(gB2 + slot * 1024 + lane * 16, sbuf + 25600 + slot * 1024);
    const u16* vc = vcrG + (size_t)(nv * 64) * 8192;
    #pragma unroll
    for (int m = 0; m < 4; m++)
      vA[m] = *(const u16x4*)&vc[((m * 8 + vgrp) * 64 + lane) * 4];
  }
  __syncthreads();
  for (int c = 0; c < 64; c += 2){
    scan_chunk(sbuf,         sbuf + 58368, vA, vB, c,
               scanA, scanBg, vcrG, coreB, sST, sVnT, sVeT, S,
               nv, h, vg, wave, lane, vgrp, myv, swv);
    scan_chunk(sbuf + 58368, sbuf,         vB, vA, c + 1,
               scanA, scanBg, vcrG, coreB, sST, sVnT, sVeT, S,
               nv, h, vg, wave, lane, vgrp, myv, swv);
  }
}

// ---------------- RMSNorm * norm_weight * silu(z) -> bf16 ----------------
__global__ __launch_bounds__(256) void k_gate(const u16* __restrict__ coreB, const u16* __restrict__ zB,
                                              const float* __restrict__ nw, u16* __restrict__ hb){
  int wave = threadIdx.x >> 6, lane = threadIdx.x & 63;
  int row = blockIdx.x * 4 + wave;    // s*32 + nv
  int s = row >> 5, nv = row & 31;
  u16x2 cu = *(const u16x2*)&coreB[(size_t)row * 128 + lane * 2];
  float c0 = bf2f(cu[0]), c1 = bf2f(cu[1]);
  float ss = c0 * c0 + c1 * c1;
  #pragma unroll
  for (int off = 32; off; off >>= 1) ss += __shfl_xor(ss, off);
  float rms = rsqrtf(ss * (1.f / 128.f) + 1e-6f);
  int zcol = (nv >> 1) * 256 + (nv & 1) * 128 + lane * 2;
  u16x2 zu = *(const u16x2*)&zB[(size_t)s * 4096 + zcol];
  float z0 = siluf(bf2f(zu[0])), z1 = siluf(bf2f(zu[1]));
  u16x2 ho;
  ho[0] = f2bf(c0 * rms * nw[lane * 2]     * z0);
  ho[1] = f2bf(c1 * rms * nw[lane * 2 + 1] * z1);
  *(u16x2*)&hb[(size_t)row * 128 + lane * 2] = ho;
}

extern "C" void kernel_launch(void* const* d_in, const int* in_sizes, int n_in,
                              void* d_out, int out_size, void* d_ws, size_t ws_size,
                              hipStream_t stream){
  (void)in_sizes; (void)n_in; (void)out_size; (void)ws_size;
  const float* hs    = (const float*)d_in[0];
  const float* Wqkvz = (const float*)d_in[1];
  const float* Wba   = (const float*)d_in[2];
  const float* cw    = (const float*)d_in[3];
  const float* dtb   = (const float*)d_in[4];
  const float* Alog  = (const float*)d_in[5];
  const float* nw    = (const float*)d_in[6];
  const float* Wout  = (const float*)d_in[7];
  char* ws = (char*)d_ws;
  const size_t MB = 1ull << 20;
  u16*   hsb   = (u16*)  (ws + 0);
  u16*   wqT   = (u16*)  (ws + 16 * MB);
  float* qcF   = (float*)(ws + 0);
  u16*   vcrG  = (u16*)  (ws + 0);
  u16*   hb    = (u16*)  (ws + 0);
  u16*   vcB   = (u16*)  (ws + 32 * MB);
  u16*   qkvB  = (u16*)  (ws + 64 * MB);
  char*  scanA =         (ws + 64 * MB);
  float* ba    = (float*)(ws + 114 * MB);
  float* betaB = (float*)(ws + 115 * MB);
  float* gB    = (float*)(ws + 115 * MB + 512 * 1024);
  u16*   zB    = (u16*)  (ws + 128 * MB);
  u16*   qcB   = (u16*)  (ws + 160 * MB);
  u16*   kcB   = (u16*)  (ws + 176 * MB);
  u16*   coreB = (u16*)  (ws + 160 * MB);
  float* kcF   = (float*)(ws + 192 * MB);
  char*  scanBg=         (ws + 192 * MB);
  u16*   woT   = (u16*)  (ws + 192 * MB);
  float* out   = (float*)d_out;

  k_cast<<<8192, 256, 0, stream>>>(hs, hsb, 2097152);
  k_trans<1><<<dim3(384, 64), dim3(32, 8), 0, stream>>>(Wqkvz, wqT, 2048, 12288);
  k_gemm256<2><<<768, 512, 0, stream>>>(hsb, wqT, qkvB, zB, 12288, 2048);
  k_conv<<<16384, 256, 0, stream>>>(qkvB, cw, qcF, kcF, vcB);
  k_ba<<<256, 256, 0, stream>>>(hs, Wba, ba);
  k_bg<<<512, 256, 0, stream>>>(ba, Alog, dtb, betaB, gB);
  k_rownorm<<<32768, 256, 0, stream>>>(qcF, kcF, qcB, kcB);
  k_pre<<<2048, 256, 0, stream>>>(qcB, kcB, vcB, betaB, gB, scanA, scanBg, vcrG);
  k_scan<<<64, 256, 0, stream>>>(scanA, scanBg, vcrG, coreB);
  k_gate<<<32768, 256, 0, stream>>>(coreB, zB, nw, hb);
  k_trans<0><<<dim3(64, 128), dim3(32, 8), 0, stream>>>(Wout, woT, 4096, 2048);
  k_gemm<0><<<dim3(16, 32), 256, 0, stream>>>(hb, woT, out, nullptr, 2048, 4096);
}

// Round 6
// 1148.436 us; speedup vs baseline: 1.6822x; 1.1278x over previous
//
#include <hip/hip_runtime.h>

typedef unsigned short u16;
typedef __attribute__((ext_vector_type(2))) float f32x2;
typedef __attribute__((ext_vector_type(4))) float f32x4;
typedef __attribute__((ext_vector_type(2))) u16 u16x2;
typedef __attribute__((ext_vector_type(4))) u16 u16x4;
typedef __attribute__((ext_vector_type(8))) u16 u16x8;
typedef __attribute__((ext_vector_type(8))) __bf16 bf16x8;

__device__ __forceinline__ float bf2f(u16 u){ unsigned v = ((unsigned)u) << 16; return __builtin_bit_cast(float, v); }
__device__ __forceinline__ u16 f2bf(float f){
  unsigned u = __builtin_bit_cast(unsigned, f);
  u += 0x7fffu + ((u >> 16) & 1u);
  return (u16)(u >> 16);
}
__device__ __forceinline__ f32x4 b4f(u16x4 u){
  f32x4 r; r[0] = bf2f(u[0]); r[1] = bf2f(u[1]); r[2] = bf2f(u[2]); r[3] = bf2f(u[3]); return r;
}
__device__ __forceinline__ u16x4 p4(f32x4 v){
  u16x4 o; o[0] = f2bf(v[0]); o[1] = f2bf(v[1]); o[2] = f2bf(v[2]); o[3] = f2bf(v[3]); return o;
}
__device__ __forceinline__ void gld16(const void* g, const void* l){
  __builtin_amdgcn_global_load_lds((__attribute__((address_space(1))) void*)(void*)g,
                                   (__attribute__((address_space(3))) void*)(void*)l, 16, 0, 0);
}
__device__ __forceinline__ float sigmoidf(float x){ return 1.f / (1.f + expf(-x)); }
__device__ __forceinline__ float siluf(float x){ return x / (1.f + expf(-x)); }

#define GBAR() do { asm volatile("" ::: "memory"); __builtin_amdgcn_s_barrier(); asm volatile("" ::: "memory"); } while(0)

// ---------------- cast fp32 -> bf16 ----------------
__global__ __launch_bounds__(256) void k_cast(const float* __restrict__ in, u16* __restrict__ out, int n4){
  int t = blockIdx.x * 256 + threadIdx.x;
  if (t >= n4) return;
  f32x4 v = ((const f32x4*)in)[t];
  u16x4 o;
  o[0] = f2bf(v[0]); o[1] = f2bf(v[1]); o[2] = f2bf(v[2]); o[3] = f2bf(v[3]);
  ((u16x4*)out)[t] = o;
}

// ---------------- transpose + cast: in (K x N) f32 -> out (N x K) bf16 ----------------
template<int PERM>
__global__ __launch_bounds__(256) void k_trans(const float* __restrict__ in, u16* __restrict__ out, int K, int N){
  __shared__ float tile[32][33];
  int tx = threadIdx.x, ty = threadIdx.y;
  int n0 = blockIdx.x * 32, k0 = blockIdx.y * 32;
  #pragma unroll
  for (int j = 0; j < 32; j += 8) tile[ty + j][tx] = in[(size_t)(k0 + ty + j) * N + n0 + tx];
  __syncthreads();
  #pragma unroll
  for (int j = 0; j < 32; j += 8){
    int n = n0 + ty + j;
    int np;
    if (PERM){
      int g = n / 768, r = n - g * 768;
      np = (r < 512) ? (g * 512 + r) : (8192 + g * 256 + (r - 512));
    } else np = n;
    out[(size_t)np * K + k0 + tx] = f2bf(tile[tx][ty + j]);
  }
}

// ============ 256x256 8-phase pipelined bf16 GEMM (T1+T2+T3+T4+T5) ============
template<int MODE>  // 0: f32 out ; 2: split bf16 out (col<8192 -> C w8192, else C2 w4096)
__global__ __launch_bounds__(512) void k_gemm256(const u16* __restrict__ A, const u16* __restrict__ Bt,
                                                 void* __restrict__ C, void* __restrict__ C2, int N, int K){
  __shared__ alignas(16) char lds[131072];
  const int tid = threadIdx.x;
  const int wid = tid >> 6, lane = tid & 63;
  const int vl = lane & 15, kg = lane >> 4;
  const int wm = wid >> 2, wn = wid & 3;
  const int nwg = (int)gridDim.x;
  const int swzb = ((int)blockIdx.x & 7) * (nwg >> 3) + ((int)blockIdx.x >> 3);
  const int nbx = N >> 8;
  const int bx = swzb % nbx, by = swzb / nbx;
  const int gm = by << 8, gn = bx << 8;
  const int nt = K >> 6;

  auto stageA = [&](int t, int h){
    if (t >= nt) return;
    const int k0 = t << 6;
    char* slot = lds + ((t & 1) * 2 + h) * 16384;
    #pragma unroll
    for (int p = 0; p < 2; p++){
      int o = p * 8192 + wid * 1024 + lane * 16;
      int sr = o >> 7, cs = (o >> 4) & 7;
      int gr = gm + ((sr >> 6) << 7) + h * 64 + (sr & 63);
      int gc = k0 + ((cs ^ (sr & 7)) << 3);
      gld16(A + (size_t)gr * K + gc, slot + p * 8192 + wid * 1024);
    }
  };
  auto stageB = [&](int t, int h){
    if (t >= nt) return;
    const int k0 = t << 6;
    char* slot = lds + 65536 + ((t & 1) * 2 + h) * 16384;
    #pragma unroll
    for (int p = 0; p < 2; p++){
      int o = p * 8192 + wid * 1024 + lane * 16;
      int sr = o >> 7, cs = (o >> 4) & 7;
      int gr = gn + ((sr >> 5) << 6) + h * 32 + (sr & 31);
      int gc = k0 + ((cs ^ (sr & 7)) << 3);
      gld16(Bt + (size_t)gr * K + gc, slot + p * 8192 + wid * 1024);
    }
  };

  f32x4 acc[8][4];
  #pragma unroll
  for (int a = 0; a < 8; a++)
    #pragma unroll
    for (int b = 0; b < 4; b++) acc[a][b] = 0.f;

  stageA(0, 0); stageB(0, 0); stageA(0, 1); stageB(0, 1); stageA(1, 0); stageB(1, 0);
  asm volatile("s_waitcnt vmcnt(8)" ::: "memory");
  GBAR();

#define PHASE(MH, NH, STAGECALL, VMSEL) do { \
    const char* Asl_ = lds + ((cur * 2 + (MH)) * 16384); \
    const char* Bsl_ = lds + 65536 + ((cur * 2 + (NH)) * 16384); \
    bf16x8 af_[4][2], bf_[2][2]; \
    _Pragma("unroll") \
    for (int mi = 0; mi < 4; mi++){ \
      int sr = wm * 64 + mi * 16 + vl; \
      _Pragma("unroll") \
      for (int ks = 0; ks < 2; ks++) \
        af_[mi][ks] = __builtin_bit_cast(bf16x8, *(const u16x8*)(Asl_ + sr * 128 + (((ks * 4 + kg) ^ (vl & 7)) << 4))); \
    } \
    _Pragma("unroll") \
    for (int ni = 0; ni < 2; ni++){ \
      int br = wn * 32 + ni * 16 + vl; \
      _Pragma("unroll") \
      for (int ks = 0; ks < 2; ks++) \
        bf_[ni][ks] = __builtin_bit_cast(bf16x8, *(const u16x8*)(Bsl_ + br * 128 + (((ks * 4 + kg) ^ (vl & 7)) << 4))); \
    } \
    STAGECALL; \
    __builtin_amdgcn_s_setprio(1); \
    _Pragma("unroll") \
    for (int mi = 0; mi < 4; mi++) \
      _Pragma("unroll") \
      for (int ni = 0; ni < 2; ni++) \
        _Pragma("unroll") \
        for (int ks = 0; ks < 2; ks++) \
          acc[(MH) * 4 + mi][(NH) * 2 + ni] = __builtin_amdgcn_mfma_f32_16x16x32_bf16(af_[mi][ks], bf_[ni][ks], acc[(MH) * 4 + mi][(NH) * 2 + ni], 0, 0, 0); \
    __builtin_amdgcn_s_setprio(0); \
    VMSEL; \
    GBAR(); \
  } while (0)

  for (int t = 0; t < nt; t++){
    const int cur = t & 1;
    const bool tail = (t >= nt - 3);
    PHASE(0, 0, stageA(t + 1, 1),
          { if (!tail) asm volatile("s_waitcnt vmcnt(6)" ::: "memory");
            else       asm volatile("s_waitcnt vmcnt(0)" ::: "memory"); });
    PHASE(0, 1, stageB(t + 1, 1), {});
    PHASE(1, 0, stageA(t + 2, 0), {});
    PHASE(1, 1, stageB(t + 2, 0),
          { if (!tail) asm volatile("s_waitcnt vmcnt(8)" ::: "memory");
            else       asm volatile("s_waitcnt vmcnt(0)" ::: "memory"); });
  }
#undef PHASE

  #pragma unroll
  for (int a = 0; a < 8; a++){
    int row = gm + wm * 128 + (a >> 2) * 64 + (a & 3) * 16 + (lane >> 4) * 4;
    #pragma unroll
    for (int b = 0; b < 4; b++){
      int col = gn + wn * 64 + (b >> 1) * 32 + (b & 1) * 16 + vl;
      #pragma unroll
      for (int j = 0; j < 4; j++){
        if (MODE == 0){
          ((float*)C)[(size_t)(row + j) * N + col] = acc[a][b][j];
        } else {
          if (col < 8192) ((u16*)C)[(size_t)(row + j) * 8192 + col]         = f2bf(acc[a][b][j]);
          else            ((u16*)C2)[(size_t)(row + j) * 4096 + col - 8192] = f2bf(acc[a][b][j]);
        }
      }
    }
  }
}

// ---------------- bf16 GEMM (m97 structure, + XCD swizzle) — used for GEMM2 ----------------
template<int MODE>
__global__ __launch_bounds__(256) void k_gemm(const u16* __restrict__ A, const u16* __restrict__ Bt,
                                              void* __restrict__ C, void* __restrict__ C2, int N, int K){
  __shared__ u16 As[128 * 32];
  __shared__ u16 Bs[128 * 32];
  const int tid = threadIdx.x;
  const int wave = tid >> 6, lane = tid & 63;
  const int nbx = (int)gridDim.x;
  const int nwg = nbx * (int)gridDim.y;
  const int linear = (int)blockIdx.y * nbx + (int)blockIdx.x;
  const int swz = (linear & 7) * (nwg >> 3) + (linear >> 3);
  const int gm = (swz / nbx) * 128, gn = (swz % nbx) * 128;
  const int c0 = wave * 2, c1 = c0 + 1;
  const int r0 = c0 * 16 + (lane >> 2), r1 = r0 + 16;
  const int kp = (lane & 3) * 8;
  const u16* a0 = A + (size_t)(gm + r0) * K + kp;
  const u16* a1 = A + (size_t)(gm + r1) * K + kp;
  const u16* b0 = Bt + (size_t)(gn + r0) * K + kp;
  const u16* b1 = Bt + (size_t)(gn + r1) * K + kp;
  const int wr = (wave >> 1) * 64, wc = (wave & 1) * 64;
  f32x4 acc[4][4];
  #pragma unroll
  for (int m = 0; m < 4; m++)
    #pragma unroll
    for (int n = 0; n < 4; n++) acc[m][n] = 0.f;
  for (int k0 = 0; k0 < K; k0 += 32){
    __syncthreads();
    gld16(a0 + k0, &As[c0 * 512]);
    gld16(a1 + k0, &As[c1 * 512]);
    gld16(b0 + k0, &Bs[c0 * 512]);
    gld16(b1 + k0, &Bs[c1 * 512]);
    __syncthreads();
    bf16x8 af[4], bfv[4];
    #pragma unroll
    for (int m = 0; m < 4; m++)
      af[m] = __builtin_bit_cast(bf16x8, *(const u16x8*)&As[(wr + m * 16 + (lane & 15)) * 32 + (lane >> 4) * 8]);
    #pragma unroll
    for (int n = 0; n < 4; n++)
      bfv[n] = __builtin_bit_cast(bf16x8, *(const u16x8*)&Bs[(wc + n * 16 + (lane & 15)) * 32 + (lane >> 4) * 8]);
    #pragma unroll
    for (int m = 0; m < 4; m++)
      #pragma unroll
      for (int n = 0; n < 4; n++)
        acc[m][n] = __builtin_amdgcn_mfma_f32_16x16x32_bf16(af[m], bfv[n], acc[m][n], 0, 0, 0);
  }
  #pragma unroll
  for (int m = 0; m < 4; m++){
    int row = gm + wr + m * 16 + (lane >> 4) * 4;
    #pragma unroll
    for (int n = 0; n < 4; n++){
      int col = gn + wc + n * 16 + (lane & 15);
      #pragma unroll
      for (int j = 0; j < 4; j++){
        if (MODE == 0){
          ((float*)C)[(size_t)(row + j) * N + col] = acc[m][n][j];
        } else {
          if (col < 8192) ((u16*)C)[(size_t)(row + j) * 8192 + col]         = f2bf(acc[m][n][j]);
          else            ((u16*)C2)[(size_t)(row + j) * 4096 + col - 8192] = f2bf(acc[m][n][j]);
        }
      }
    }
  }
}

// ---------------- small ba GEMM ----------------
__global__ __launch_bounds__(256) void k_ba(const float* __restrict__ hs, const float* __restrict__ Wba,
                                            float* __restrict__ ba){
  int wave = threadIdx.x >> 6, lane = threadIdx.x & 63;
  int s0 = (blockIdx.x * 4 + wave) * 4;
  f32x4 acc = 0.f;
  for (int k = 0; k < 2048; k += 4){
    float w0 = Wba[(size_t)(k + 0) * 64 + lane];
    float w1 = Wba[(size_t)(k + 1) * 64 + lane];
    float w2 = Wba[(size_t)(k + 2) * 64 + lane];
    float w3 = Wba[(size_t)(k + 3) * 64 + lane];
    f32x4 h0 = *(const f32x4*)&hs[(size_t)(s0 + 0) * 2048 + k];
    f32x4 h1 = *(const f32x4*)&hs[(size_t)(s0 + 1) * 2048 + k];
    f32x4 h2 = *(const f32x4*)&hs[(size_t)(s0 + 2) * 2048 + k];
    f32x4 h3 = *(const f32x4*)&hs[(size_t)(s0 + 3) * 2048 + k];
    acc[0] += h0[0]*w0 + h0[1]*w1 + h0[2]*w2 + h0[3]*w3;
    acc[1] += h1[0]*w0 + h1[1]*w1 + h1[2]*w2 + h1[3]*w3;
    acc[2] += h2[0]*w0 + h2[1]*w1 + h2[2]*w2 + h2[3]*w3;
    acc[3] += h3[0]*w0 + h3[1]*w1 + h3[2]*w2 + h3[3]*w3;
  }
  #pragma unroll
  for (int r = 0; r < 4; r++) ba[(size_t)(s0 + r) * 64 + lane] = acc[r];
}

// ---------------- causal dwconv(K=4)+SiLU; q/k -> f32, v -> bf16 ----------------
__global__ __launch_bounds__(256) void k_conv(const u16* __restrict__ qkvB, const float* __restrict__ cw,
                                              float* __restrict__ qcF, float* __restrict__ kcF, u16* __restrict__ vcB){
  int idx = blockIdx.x * 256 + threadIdx.x;      // 4096 * 1024
  int c8 = idx & 1023, s = idx >> 10;
  int c = c8 * 8;
  int col;
  if (c < 2048)      { int hh = c >> 7, d = c & 127; col = hh * 512 + d; }
  else if (c < 4096) { int cc = c - 2048, hh = cc >> 7, d = cc & 127; col = hh * 512 + 128 + d; }
  else               { int cc = c - 4096, nv = cc >> 7, d = cc & 127; col = (nv >> 1) * 512 + 256 + (nv & 1) * 128 + d; }
  float w[8][4];
  #pragma unroll
  for (int e = 0; e < 8; e++){
    f32x4 wv = *(const f32x4*)&cw[(size_t)(c + e) * 4];
    #pragma unroll
    for (int j = 0; j < 4; j++) w[e][j] = wv[j];
  }
  float acc[8] = {0.f,0.f,0.f,0.f,0.f,0.f,0.f,0.f};
  #pragma unroll
  for (int j = 0; j < 4; j++){
    int sp = s - 3 + j;
    if (sp < 0) continue;
    u16x8 x = *(const u16x8*)&qkvB[(size_t)sp * 8192 + col];
    #pragma unroll
    for (int e = 0; e < 8; e++) acc[e] += w[e][j] * bf2f(x[e]);
  }
  if (c < 4096){
    float* outp = (c < 2048) ? qcF + (size_t)s * 2048 + c : kcF + (size_t)s * 2048 + (c - 2048);
    f32x4 oa, ob;
    #pragma unroll
    for (int e = 0; e < 4; e++) oa[e] = siluf(acc[e]);
    #pragma unroll
    for (int e = 0; e < 4; e++) ob[e] = siluf(acc[e + 4]);
    *(f32x4*)&outp[0] = oa;
    *(f32x4*)&outp[4] = ob;
  } else {
    u16x8 ov;
    #pragma unroll
    for (int e = 0; e < 8; e++) ov[e] = f2bf(siluf(acc[e]));
    *(u16x8*)&vcB[(size_t)s * 4096 + (c - 4096)] = ov;
  }
}

// ---------------- beta / g ----------------
__global__ __launch_bounds__(256) void k_bg(const float* __restrict__ ba, const float* __restrict__ Alog,
                                            const float* __restrict__ dtb, float* __restrict__ betaO,
                                            float* __restrict__ gO){
  int idx = blockIdx.x * 256 + threadIdx.x;   // < 131072
  int s = idx >> 5, nv = idx & 31;
  float b = ba[(size_t)s * 64 + (nv >> 1) * 4 + (nv & 1)];
  float a = ba[(size_t)s * 64 + (nv >> 1) * 4 + 2 + (nv & 1)];
  betaO[idx] = sigmoidf(b);
  float x = a + dtb[nv];
  float sp = (x > 20.f) ? x : log1pf(expf(x));
  gO[idx] = -expf(Alog[nv]) * sp;
}

// ---------------- l2norm rows: f32 in -> swizzled bf16 blocks ----------------
// q rows -> scanBg block (h*64+chunk)*32768, offset 0 (16KB, swizzled)
// k rows -> kSwz block (h*64+chunk)*8192 u16 (swizzled)
__global__ __launch_bounds__(256) void k_rownorm(const float* __restrict__ qcF, const float* __restrict__ kcF,
                                                 char* __restrict__ scanBg, u16* __restrict__ kSwz){
  int wave = threadIdx.x >> 6, lane = threadIdx.x & 63;
  int row = blockIdx.x * 4 + wave;  // 0..131071; first 65536 = q rows
  bool isq = row < 65536;
  int r = isq ? row : row - 65536;
  const float* src = (isq ? qcF : kcF) + (size_t)r * 128;
  int s = r >> 4, h = r & 15;
  int chunk = s >> 6, i = s & 63;
  float sc = isq ? 0.08838834764831845f : 1.f;
  f32x2 v = ((const f32x2*)src)[lane];
  float ss = v[0] * v[0] + v[1] * v[1];
  #pragma unroll
  for (int off = 32; off; off >>= 1) ss += __shfl_xor(ss, off);
  float inv = rsqrtf(ss + 1e-6f) * sc;
  u16x2 o; o[0] = f2bf(v[0] * inv); o[1] = f2bf(v[1] * inv);
  int col = (lane * 2) ^ ((i & 7) << 3);
  if (isq) *(u16x2*)(scanBg + ((size_t)(h * 64 + chunk)) * 32768 + (size_t)(i * 128 + col) * 2) = o;
  else     *(u16x2*)&kSwz[((size_t)(h * 64 + chunk)) * 8192 + i * 128 + col] = o;
}

// ---------------- per-(nv,chunk) precompute v2: MFMA M/attn + low-LDS (3 blocks/CU) ----------------
// scanA block (stride 25600B): [kcd 16KB swz | attn 8KB swz | eg 256B | ed 256B | pad]
// scanBg block (stride 32768B, per (h,chunk)): [q 16KB swz (by rownorm) | kT 16KB swz (by even nv here)]
// vcr block (8192 u16 per (nv,chunk)): scan C-layout order
__global__ __launch_bounds__(256) void k_pre(const u16* __restrict__ kSwz, const u16* __restrict__ vcB,
    const float* __restrict__ betaB, const float* __restrict__ gB,
    char* __restrict__ scanA, char* __restrict__ scanBg, u16* __restrict__ vcrG){
  __shared__ alignas(16) u16 sKb[8192];
  __shared__ alignas(16) u16 sQb[8192];
  __shared__ float sM[64 * 68];
  __shared__ float sG[64];
  __shared__ float sEg[64];
  __shared__ float sBeta[64];
  const int tid = threadIdx.x, wave = tid >> 6, lane = tid & 63;
  const int nv = blockIdx.x & 31, chunk = blockIdx.x >> 5;
  const int h = nv >> 1, s0 = chunk * 64;
  char* gA = scanA + ((size_t)nv * 64 + chunk) * 25600;
  u16* kcdG = (u16*)gA;
  u16* attnG = (u16*)(gA + 16384);
  float* egG = (float*)(gA + 24576);
  char* gB2 = scanBg + ((size_t)h * 64 + chunk) * 32768;
  u16* ktG = (u16*)(gB2 + 16384);
  // stage K and Q (linear copy: global blocks are already swizzled)
  const char* kblk = (const char*)(kSwz + ((size_t)h * 64 + chunk) * 8192);
  const char* qblk = (const char*)gB2;
  for (int t = wave; t < 16; t += 4){
    gld16(kblk + t * 1024 + lane * 16, (char*)sKb + t * 1024);
    gld16(qblk + t * 1024 + lane * 16, (char*)sQb + t * 1024);
  }
  if (tid < 64){
    float g = gB[(size_t)(s0 + tid) * 32 + nv];
    #pragma unroll
    for (int off = 1; off < 64; off <<= 1){ float nb = __shfl_up(g, off); if (tid >= off) g += nb; }
    float g63 = __shfl(g, 63);
    float eg = expf(g);
    sG[tid] = g; sEg[tid] = eg;
    egG[tid] = eg; egG[64 + tid] = expf(g63 - g);
  } else if (tid < 128){
    sBeta[tid - 64] = betaB[(size_t)(s0 + tid - 64) * 32 + nv];
  }
  __syncthreads();
  // MFMA: M = k.k^T strip, attn = q.k^T strip ; wave owns cols [wave*16, wave*16+16)
  const int vl = lane & 15, kg = lane >> 4;
  f32x4 Mf[4], Af[4];
  #pragma unroll
  for (int m = 0; m < 4; m++){ Mf[m] = 0.f; Af[m] = 0.f; }
  const int brow = wave * 16 + vl;
  const int bs = (brow & 7) << 3;
  #pragma unroll
  for (int kt = 0; kt < 4; kt++){
    int ko = kt * 32 + kg * 8;
    bf16x8 bk = __builtin_bit_cast(bf16x8, *(const u16x8*)&sKb[brow * 128 + (ko ^ bs)]);
    #pragma unroll
    for (int m = 0; m < 4; m++){
      int ar = m * 16 + vl, as = (ar & 7) << 3;
      bf16x8 ak = __builtin_bit_cast(bf16x8, *(const u16x8*)&sKb[ar * 128 + (ko ^ as)]);
      Mf[m] = __builtin_amdgcn_mfma_f32_16x16x32_bf16(ak, bk, Mf[m], 0, 0, 0);
      bf16x8 aq = __builtin_bit_cast(bf16x8, *(const u16x8*)&sQb[ar * 128 + (ko ^ as)]);
      Af[m] = __builtin_amdgcn_mfma_f32_16x16x32_bf16(aq, bk, Af[m], 0, 0, 0);
    }
  }
  // epilogue: decay/mask; write sM (f32) and attnG (bf16 swz)
  {
    const int j = wave * 16 + vl;
    float gj = sG[j];
    #pragma unroll
    for (int m = 0; m < 4; m++){
      #pragma unroll
      for (int r = 0; r < 4; r++){
        int i = m * 16 + kg * 4 + r;
        float dec = expf(sG[i] - gj);
        sM[i * 68 + j] = (i > j) ? Mf[m][r] * sBeta[i] * dec : 0.f;
        attnG[i * 64 + (j ^ ((i & 7) << 3))] = f2bf((i >= j) ? Af[m][r] * dec : 0.f);
      }
    }
  }
  // kT transpose output (one writer per h)
  if (!(nv & 1)){
    for (int t = tid; t < 2048; t += 256){
      int k = t & 127, i0 = (t >> 7) << 2;
      u16x4 o;
      #pragma unroll
      for (int r2 = 0; r2 < 4; r2++)
        o[r2] = sKb[(i0 + r2) * 128 + (k ^ (((i0 + r2) & 7) << 3))];
      *(u16x4*)&ktG[k * 64 + (i0 ^ ((k & 7) << 3))] = o;
    }
  }
  __syncthreads();
  // forward substitution: thread owns column tid of [v_beta(128) | k_beta*eg(128)]
  float x[64];
  if (tid < 128){
    const u16* vp = vcB + (size_t)s0 * 4096 + (size_t)nv * 128 + tid;
    #pragma unroll
    for (int i = 0; i < 64; i++) x[i] = bf2f(vp[(size_t)i * 4096]) * sBeta[i];
  } else {
    int d = tid - 128;
    #pragma unroll
    for (int i = 0; i < 64; i++)
      x[i] = bf2f(sKb[i * 128 + (d ^ ((i & 7) << 3))]) * sBeta[i] * sEg[i];
  }
  #pragma unroll
  for (int i = 1; i < 64; i++){
    #pragma unroll
    for (int jj = 0; jj < i; jj++) x[i] -= sM[i * 68 + jj] * x[jj];
  }
  // direct global outputs
  if (tid < 128){
    u16* vb = vcrG + ((size_t)nv * 64 + chunk) * 8192;
    int c = tid;
    #pragma unroll
    for (int m = 0; m < 4; m++)
      #pragma unroll
      for (int r = 0; r < 4; r++){
        u16x4 a;
        #pragma unroll
        for (int q2 = 0; q2 < 4; q2++) a[q2] = f2bf(x[m * 16 + r * 4 + q2]);
        *(u16x4*)&vb[(((m * 8 + (c >> 4)) * 64) + r * 16 + (c & 15)) * 4] = a;
      }
  } else {
    int d = tid - 128;
    #pragma unroll
    for (int i = 0; i < 64; i++)
      kcdG[i * 128 + (d ^ ((i & 7) << 3))] = f2bf(x[i]);
  }
}

// ---------------- MFMA scan chunk body ----------------
__device__ __forceinline__ void scan_chunk(
    const char* CURB, char* OTHB, u16x4* VCUR, u16x4* VOTH, int CH,
    const char* scanA, const char* scanBg, const u16* vcrG, u16* coreB,
    u16* sST, u16* sVnT, u16* sVeT, f32x4* S,
    int nv, int h, int vg, int wave, int lane, int vgrp, int myv, int swv){
  const int vl = lane & 15, kg = lane >> 4;
  if (CH + 1 < 64){
    const char* gA = scanA + ((size_t)nv * 64 + CH + 1) * 25600;
    for (int slot = wave; slot < 25; slot += 4)
      gld16(gA + slot * 1024 + lane * 16, OTHB + slot * 1024);
    const char* gB2 = scanBg + ((size_t)h * 64 + CH + 1) * 32768;
    for (int slot = wave; slot < 32; slot += 4)
      gld16(gB2 + slot * 1024 + lane * 16, OTHB + 25600 + slot * 1024);
    const u16* vc = vcrG + ((size_t)nv * 64 + CH + 1) * 8192;
    #pragma unroll
    for (int m = 0; m < 4; m++)
      VOTH[m] = *(const u16x4*)&vc[((m * 8 + vgrp) * 64 + lane) * 4];
  }
  const u16* kcdL  = (const u16*)(CURB);
  const u16* attnL = (const u16*)(CURB + 16384);
  const float* egL = (const float*)(CURB + 24576);
  const u16* qL    = (const u16*)(CURB + 25600);
  const u16* ktL   = (const u16*)(CURB + 25600 + 16384);
  f32x4 vp[4], ai[4];
  #pragma unroll
  for (int m = 0; m < 4; m++){ vp[m] = 0.f; ai[m] = 0.f; }
  #pragma unroll
  for (int kt = 0; kt < 4; kt++){
    int ko = kt * 32 + kg * 8;
    bf16x8 sf = __builtin_bit_cast(bf16x8, *(const u16x8*)&sST[myv * 128 + (ko ^ swv)]);
    #pragma unroll
    for (int m = 0; m < 4; m++){
      int row = m * 16 + vl, rs = (row & 7) << 3;
      bf16x8 kf = __builtin_bit_cast(bf16x8, *(const u16x8*)&kcdL[row * 128 + (ko ^ rs)]);
      vp[m] = __builtin_amdgcn_mfma_f32_16x16x32_bf16(kf, sf, vp[m], 0, 0, 0);
      bf16x8 qf = __builtin_bit_cast(bf16x8, *(const u16x8*)&qL[row * 128 + (ko ^ rs)]);
      ai[m] = __builtin_amdgcn_mfma_f32_16x16x32_bf16(qf, sf, ai[m], 0, 0, 0);
    }
  }
  float eL = egL[63];
  #pragma unroll
  for (int m = 0; m < 4; m++){
    f32x4 vn = b4f(VCUR[m]) - vp[m];
    f32x4 ed4 = *(const f32x4*)&egL[64 + m * 16 + kg * 4];
    f32x4 eg4 = *(const f32x4*)&egL[m * 16 + kg * 4];
    int ja = (m * 16 + kg * 4) ^ swv;
    *(u16x4*)&sVnT[myv * 64 + ja] = p4(vn);
    *(u16x4*)&sVeT[myv * 64 + ja] = p4(vn * ed4);
    ai[m] *= eg4;
  }
  #pragma unroll
  for (int ms = 0; ms < 8; ms++) S[ms] *= eL;
  #pragma unroll
  for (int jt = 0; jt < 2; jt++){
    int jo = jt * 32 + kg * 8;
    bf16x8 vnf = __builtin_bit_cast(bf16x8, *(const u16x8*)&sVnT[myv * 64 + (jo ^ swv)]);
    bf16x8 vef = __builtin_bit_cast(bf16x8, *(const u16x8*)&sVeT[myv * 64 + (jo ^ swv)]);
    #pragma unroll
    for (int m = 0; m < 4; m++){
      int row = m * 16 + vl, rs = (row & 7) << 3;
      bf16x8 af = __builtin_bit_cast(bf16x8, *(const u16x8*)&attnL[row * 64 + (jo ^ rs)]);
      ai[m] = __builtin_amdgcn_mfma_f32_16x16x32_bf16(af, vnf, ai[m], 0, 0, 0);
    }
    #pragma unroll
    for (int ms = 0; ms < 8; ms++){
      int krow = ms * 16 + vl, rs = (krow & 7) << 3;
      bf16x8 kf = __builtin_bit_cast(bf16x8, *(const u16x8*)&ktL[krow * 64 + (jo ^ rs)]);
      S[ms] = __builtin_amdgcn_mfma_f32_16x16x32_bf16(kf, vef, S[ms], 0, 0, 0);
    }
  }
  #pragma unroll
  for (int m = 0; m < 4; m++){
    size_t ig = (size_t)CH * 64 + m * 16 + kg * 4;
    size_t base = (ig * 32 + nv) * 128 + vg * 64 + wave * 16 + vl;
    #pragma unroll
    for (int j = 0; j < 4; j++) coreB[base + (size_t)j * 4096] = f2bf(ai[m][j]);
  }
  #pragma unroll
  for (int ms = 0; ms < 8; ms++){
    int k0 = ms * 16 + kg * 4;
    *(u16x4*)&sST[myv * 128 + (k0 ^ swv)] = p4(S[ms]);
  }
  __syncthreads();
}

// ---------------- sequential inter-chunk scan; 64 blocks = 32 nv x 2 v-halves ----------------
__global__ __launch_bounds__(256) void k_scan(const char* __restrict__ scanA, const char* __restrict__ scanBg,
    const u16* __restrict__ vcrG, u16* __restrict__ coreB){
  __shared__ alignas(16) char sbuf[2 * 58368];
  __shared__ alignas(16) u16 sST[64 * 128];
  __shared__ alignas(16) u16 sVnT[64 * 64];
  __shared__ alignas(16) u16 sVeT[64 * 64];
  const int tid = threadIdx.x;
  const int wave = tid >> 6, lane = tid & 63;
  const int nv = blockIdx.x & 31, vg = blockIdx.x >> 5;
  const int h = nv >> 1;
  const int vgrp = vg * 4 + wave;
  const int myv = wave * 16 + (lane & 15);
  const int swv = (myv & 7) << 3;
  for (int t = tid; t < 8192; t += 256) sST[t] = 0;
  f32x4 S[8];
  #pragma unroll
  for (int ms = 0; ms < 8; ms++) S[ms] = 0.f;
  u16x4 vA[4], vB[4];
  {
    const char* gA = scanA + (size_t)(nv * 64) * 25600;
    for (int slot = wave; slot < 25; slot += 4)
      gld16(gA + slot * 1024 + lane * 16, sbuf + slot * 1024);
    const char* gB2 = scanBg + (size_t)(h * 64) * 32768;
    for (int slot = wave; slot < 32; slot += 4)
      gld16(gB2 + slot * 1024 + lane * 16, sbuf + 25600 + slot * 1024);
    const u16* vc = vcrG + (size_t)(nv * 64) * 8192;
    #pragma unroll
    for (int m = 0; m < 4; m++)
      vA[m] = *(const u16x4*)&vc[((m * 8 + vgrp) * 64 + lane) * 4];
  }
  __syncthreads();
  for (int c = 0; c < 64; c += 2){
    scan_chunk(sbuf,         sbuf + 58368, vA, vB, c,
               scanA, scanBg, vcrG, coreB, sST, sVnT, sVeT, S,
               nv, h, vg, wave, lane, vgrp, myv, swv);
    scan_chunk(sbuf + 58368, sbuf,         vB, vA, c + 1,
               scanA, scanBg, vcrG, coreB, sST, sVnT, sVeT, S,
               nv, h, vg, wave, lane, vgrp, myv, swv);
  }
}

// ---------------- RMSNorm * norm_weight * silu(z) -> bf16 ----------------
__global__ __launch_bounds__(256) void k_gate(const u16* __restrict__ coreB, const u16* __restrict__ zB,
                                              const float* __restrict__ nw, u16* __restrict__ hb){
  int wave = threadIdx.x >> 6, lane = threadIdx.x & 63;
  int row = blockIdx.x * 4 + wave;    // s*32 + nv
  int s = row >> 5, nv = row & 31;
  u16x2 cu = *(const u16x2*)&coreB[(size_t)row * 128 + lane * 2];
  float c0 = bf2f(cu[0]), c1 = bf2f(cu[1]);
  float ss = c0 * c0 + c1 * c1;
  #pragma unroll
  for (int off = 32; off; off >>= 1) ss += __shfl_xor(ss, off);
  float rms = rsqrtf(ss * (1.f / 128.f) + 1e-6f);
  int zcol = (nv >> 1) * 256 + (nv & 1) * 128 + lane * 2;
  u16x2 zu = *(const u16x2*)&zB[(size_t)s * 4096 + zcol];
  float z0 = siluf(bf2f(zu[0])), z1 = siluf(bf2f(zu[1]));
  u16x2 ho;
  ho[0] = f2bf(c0 * rms * nw[lane * 2]     * z0);
  ho[1] = f2bf(c1 * rms * nw[lane * 2 + 1] * z1);
  *(u16x2*)&hb[(size_t)row * 128 + lane * 2] = ho;
}

extern "C" void kernel_launch(void* const* d_in, const int* in_sizes, int n_in,
                              void* d_out, int out_size, void* d_ws, size_t ws_size,
                              hipStream_t stream){
  (void)in_sizes; (void)n_in; (void)out_size; (void)ws_size;
  const float* hs    = (const float*)d_in[0];
  const float* Wqkvz = (const float*)d_in[1];
  const float* Wba   = (const float*)d_in[2];
  const float* cw    = (const float*)d_in[3];
  const float* dtb   = (const float*)d_in[4];
  const float* Alog  = (const float*)d_in[5];
  const float* nw    = (const float*)d_in[6];
  const float* Wout  = (const float*)d_in[7];
  char* ws = (char*)d_ws;
  const size_t MB = 1ull << 20;
  // 0-32:    hsb(0-16)+wqT head -> qcF f32 -> vcrG bf16 -> hb bf16
  // 16-64:   wqT -> vcB bf16 (32-64)
  // 64-128:  qkvB -> scanA(64-114) + ba/betaB/gB(114-116)
  // 128-160: zB
  // 160-192: kcF f32 -> coreB bf16
  // 192-224: scanBg (rownorm q + pre kT) -> woT
  // 224-240: kSwz
  u16*   hsb   = (u16*)  (ws + 0);
  u16*   wqT   = (u16*)  (ws + 16 * MB);
  float* qcF   = (float*)(ws + 0);
  u16*   vcrG  = (u16*)  (ws + 0);
  u16*   hb    = (u16*)  (ws + 0);
  u16*   vcB   = (u16*)  (ws + 32 * MB);
  u16*   qkvB  = (u16*)  (ws + 64 * MB);
  char*  scanA =         (ws + 64 * MB);
  float* ba    = (float*)(ws + 114 * MB);
  float* betaB = (float*)(ws + 115 * MB);
  float* gB    = (float*)(ws + 115 * MB + 512 * 1024);
  u16*   zB    = (u16*)  (ws + 128 * MB);
  float* kcF   = (float*)(ws + 160 * MB);
  u16*   coreB = (u16*)  (ws + 160 * MB);
  char*  scanBg=         (ws + 192 * MB);
  u16*   woT   = (u16*)  (ws + 192 * MB);
  u16*   kSwz  = (u16*)  (ws + 224 * MB);
  float* out   = (float*)d_out;

  k_cast<<<8192, 256, 0, stream>>>(hs, hsb, 2097152);
  k_trans<1><<<dim3(384, 64), dim3(32, 8), 0, stream>>>(Wqkvz, wqT, 2048, 12288);
  k_gemm256<2><<<768, 512, 0, stream>>>(hsb, wqT, qkvB, zB, 12288, 2048);
  k_conv<<<16384, 256, 0, stream>>>(qkvB, cw, qcF, kcF, vcB);
  k_ba<<<256, 256, 0, stream>>>(hs, Wba, ba);
  k_bg<<<512, 256, 0, stream>>>(ba, Alog, dtb, betaB, gB);
  k_rownorm<<<32768, 256, 0, stream>>>(qcF, kcF, scanBg, kSwz);
  k_pre<<<2048, 256, 0, stream>>>(kSwz, vcB, betaB, gB, scanA, scanBg, vcrG);
  k_scan<<<64, 256, 0, stream>>>(scanA, scanBg, vcrG, coreB);
  k_gate<<<32768, 256, 0, stream>>>(coreB, zB, nw, hb);
  k_trans<0><<<dim3(64, 128), dim3(32, 8), 0, stream>>>(Wout, woT, 4096, 2048);
  k_gemm<0><<<dim3(16, 32), 256, 0, stream>>>(hb, woT, out, nullptr, 2048, 4096);
}